// Round 1
// baseline (2181.356 us; speedup 1.0000x reference)
//
#include <hip/hip_runtime.h>
#include <hip/hip_bf16.h>
#include <cstddef>

// ---------------- degrees ----------------
__global__ void k_deg(const int* __restrict__ S, const int* __restrict__ R,
                      int* degS, int* degR, int nE) {
    int e = blockIdx.x * blockDim.x + threadIdx.x;
    if (e < nE) {
        atomicAdd(&degS[S[e]], 1);
        atomicAdd(&degR[R[e]], 1);
    }
}

__global__ void k_inv(const int* __restrict__ degS, const int* __restrict__ degR,
                      float* inv_s, float* inv_r, int nN) {
    int n = blockIdx.x * blockDim.x + threadIdx.x;
    if (n < nN) {
        inv_s[n] = rsqrtf(fmaxf((float)degS[n], 1.0f));
        inv_r[n] = rsqrtf(fmaxf((float)degR[n], 1.0f));
    }
}

// ---------------- layer 1 dense: x[N,9] @ W1[9,64] + b1, * inv_s ----------------
__global__ void k_lin1(const float* __restrict__ x, const float* __restrict__ W,
                       const float* __restrict__ b, const float* __restrict__ inv_s,
                       float* __restrict__ out, int nN) {
    __shared__ float Wl[9 * 64];
    __shared__ float bl[64];
    for (int i = threadIdx.x; i < 9 * 64; i += blockDim.x) Wl[i] = W[i];
    if (threadIdx.x < 64) bl[threadIdx.x] = b[threadIdx.x];
    __syncthreads();
    int n = blockIdx.x * blockDim.x + threadIdx.x;
    if (n >= nN) return;
    float xv[9];
#pragma unroll
    for (int k = 0; k < 9; k++) xv[k] = x[(size_t)n * 9 + k];
    float sc = inv_s[n];
    float* o = out + (size_t)n * 64;
#pragma unroll
    for (int c = 0; c < 4; c++) {
        float acc[16];
#pragma unroll
        for (int j = 0; j < 16; j++) acc[j] = bl[c * 16 + j];
#pragma unroll
        for (int k = 0; k < 9; k++) {
#pragma unroll
            for (int j = 0; j < 16; j++) acc[j] += xv[k] * Wl[k * 64 + c * 16 + j];
        }
#pragma unroll
        for (int q = 0; q < 4; q++) {
            float4 v = make_float4(acc[4 * q + 0] * sc, acc[4 * q + 1] * sc,
                                   acc[4 * q + 2] * sc, acc[4 * q + 3] * sc);
            *(float4*)(o + c * 16 + 4 * q) = v;
        }
    }
}

// ---------------- layer 2 dense: relu(in*inv_r)[N,64] @ W2[64,128] + b2, * inv_s ----------------
__global__ void k_lin2(const float* __restrict__ in, const float* __restrict__ W,
                       const float* __restrict__ b, const float* __restrict__ inv_r,
                       const float* __restrict__ inv_s, float* __restrict__ out, int nN) {
    __shared__ float Wl[64 * 128];  // 32 KB
    __shared__ float bl[128];
    for (int i = threadIdx.x; i < 64 * 128; i += blockDim.x) Wl[i] = W[i];
    for (int i = threadIdx.x; i < 128; i += blockDim.x) bl[i] = b[i];
    __syncthreads();
    int n = blockIdx.x * blockDim.x + threadIdx.x;
    if (n >= nN) return;
    float ir = inv_r[n];
    float sc = inv_s[n];
    float xv[64];
    const float4* xin = (const float4*)(in + (size_t)n * 64);
#pragma unroll
    for (int k4 = 0; k4 < 16; k4++) {
        float4 v = xin[k4];
        xv[4 * k4 + 0] = fmaxf(v.x * ir, 0.0f);
        xv[4 * k4 + 1] = fmaxf(v.y * ir, 0.0f);
        xv[4 * k4 + 2] = fmaxf(v.z * ir, 0.0f);
        xv[4 * k4 + 3] = fmaxf(v.w * ir, 0.0f);
    }
    float* o = out + (size_t)n * 128;
#pragma unroll
    for (int c = 0; c < 8; c++) {
        float acc[16];
#pragma unroll
        for (int j = 0; j < 16; j++) acc[j] = bl[c * 16 + j];
#pragma unroll 8
        for (int k = 0; k < 64; k++) {
#pragma unroll
            for (int j = 0; j < 16; j++) acc[j] += xv[k] * Wl[k * 128 + c * 16 + j];
        }
#pragma unroll
        for (int q = 0; q < 4; q++) {
            float4 v = make_float4(acc[4 * q + 0] * sc, acc[4 * q + 1] * sc,
                                   acc[4 * q + 2] * sc, acc[4 * q + 3] * sc);
            *(float4*)(o + c * 16 + 4 * q) = v;
        }
    }
}

// ---------------- layer 3 dense: relu(in*inv_r)[N,128] @ W3[128,2] + b3, * inv_s ----------------
__global__ void k_lin3(const float* __restrict__ in, const float* __restrict__ W,
                       const float* __restrict__ b, const float* __restrict__ inv_r,
                       const float* __restrict__ inv_s, float* __restrict__ out, int nN) {
    __shared__ float Wl[128 * 2];
    __shared__ float bl[2];
    for (int i = threadIdx.x; i < 256; i += blockDim.x) Wl[i] = W[i];
    if (threadIdx.x < 2) bl[threadIdx.x] = b[threadIdx.x];
    __syncthreads();
    int n = blockIdx.x * blockDim.x + threadIdx.x;
    if (n >= nN) return;
    float ir = inv_r[n];
    float sc = inv_s[n];
    float acc0 = bl[0], acc1 = bl[1];
    const float4* xin = (const float4*)(in + (size_t)n * 128);
#pragma unroll 8
    for (int k4 = 0; k4 < 32; k4++) {
        float4 v = xin[k4];
        float a = fmaxf(v.x * ir, 0.0f);
        float bb = fmaxf(v.y * ir, 0.0f);
        float cc = fmaxf(v.z * ir, 0.0f);
        float dd = fmaxf(v.w * ir, 0.0f);
        int k = 4 * k4;
        acc0 += a * Wl[(k + 0) * 2] + bb * Wl[(k + 1) * 2] + cc * Wl[(k + 2) * 2] + dd * Wl[(k + 3) * 2];
        acc1 += a * Wl[(k + 0) * 2 + 1] + bb * Wl[(k + 1) * 2 + 1] + cc * Wl[(k + 2) * 2 + 1] + dd * Wl[(k + 3) * 2 + 1];
    }
    *(float2*)(out + (size_t)n * 2) = make_float2(acc0 * sc, acc1 * sc);
}

// ---------------- scatter kernels (wave per edge) ----------------
__global__ void k_scatter64(const float* __restrict__ A, float* B,
                            const int* __restrict__ S, const int* __restrict__ R, int nE) {
    int gid = blockIdx.x * blockDim.x + threadIdx.x;
    int w = gid >> 6;
    int lane = threadIdx.x & 63;
    if (w >= nE) return;
    int s = S[w], r = R[w];
    float v = A[(size_t)s * 64 + lane];
    atomicAdd(&B[(size_t)r * 64 + lane], v);
}

__global__ void k_scatter128(const float* __restrict__ A, float* B,
                             const int* __restrict__ S, const int* __restrict__ R, int nE) {
    int gid = blockIdx.x * blockDim.x + threadIdx.x;
    int w = gid >> 6;
    int lane = threadIdx.x & 63;
    if (w >= nE) return;
    int s = S[w], r = R[w];
    float2 v = ((const float2*)(A + (size_t)s * 128))[lane];
    atomicAdd(&B[(size_t)r * 128 + 2 * lane + 0], v.x);
    atomicAdd(&B[(size_t)r * 128 + 2 * lane + 1], v.y);
}

__global__ void k_scatter2(const float* __restrict__ A, float* B,
                           const int* __restrict__ S, const int* __restrict__ R, int nE) {
    int e = blockIdx.x * blockDim.x + threadIdx.x;
    if (e >= nE) return;
    int s = S[e], r = R[e];
    float2 v = ((const float2*)A)[s];
    atomicAdd(&B[2 * r + 0], v.x);
    atomicAdd(&B[2 * r + 1], v.y);
}

// ---------------- graph pooling: segment_sum(in*inv_r, batch) ----------------
__global__ void k_pool(const float* __restrict__ in, const float* __restrict__ inv_r,
                       const int* __restrict__ batch, float* out, int nN, int outSize) {
    __shared__ float sm[256];
    if (threadIdx.x < 256) sm[threadIdx.x] = 0.0f;
    __syncthreads();
    int n = blockIdx.x * blockDim.x + threadIdx.x;
    if (n < nN) {
        float ir = inv_r[n];
        float2 v = ((const float2*)in)[n];
        int g = batch[n];
        atomicAdd(&sm[2 * g + 0], v.x * ir);
        atomicAdd(&sm[2 * g + 1], v.y * ir);
    }
    __syncthreads();
    if (threadIdx.x < (unsigned)outSize) atomicAdd(&out[threadIdx.x], sm[threadIdx.x]);
}

extern "C" void kernel_launch(void* const* d_in, const int* in_sizes, int n_in,
                              void* d_out, int out_size, void* d_ws, size_t ws_size,
                              hipStream_t stream) {
    const float* x     = (const float*)d_in[0];
    const int*   S     = (const int*)d_in[1];
    const int*   R     = (const int*)d_in[2];
    const int*   batch = (const int*)d_in[3];
    // d_in[4] = num_graphs scalar (derived from out_size instead)
    const float* W1 = (const float*)d_in[5];
    const float* b1 = (const float*)d_in[6];
    const float* W2 = (const float*)d_in[7];
    const float* b2 = (const float*)d_in[8];
    const float* W3 = (const float*)d_in[9];
    const float* b3 = (const float*)d_in[10];

    int nN = in_sizes[0] / 9;
    int nE = in_sizes[1];

    char* ws = (char*)d_ws;
    int*   degS  = (int*)ws;
    int*   degR  = degS + nN;
    float* inv_s = (float*)(ws + (size_t)2 * nN * 4);
    float* inv_r = inv_s + nN;
    float* bufA  = (float*)(ws + (size_t)4 * nN * 4);            // [nN,128]
    float* bufB  = bufA + (size_t)nN * 128;                       // [nN,128]
    float* bufC  = bufA;                                          // [nN,2] (bufA free by then)
    float* bufD  = bufA + (size_t)nN * 2;                         // [nN,2]

    const int B = 256;
    int gN = (nN + B - 1) / B;
    int gE = (nE + B - 1) / B;
    int gEw = (int)(((size_t)nE * 64 + B - 1) / B);  // wave-per-edge grids

    // degrees (once; same for all layers)
    hipMemsetAsync(degS, 0, (size_t)2 * nN * 4, stream);
    k_deg<<<gE, B, 0, stream>>>(S, R, degS, degR, nE);
    k_inv<<<gN, B, 0, stream>>>(degS, degR, inv_s, inv_r, nN);

    // layer 1: 9 -> 64
    k_lin1<<<gN, B, 0, stream>>>(x, W1, b1, inv_s, bufA, nN);
    hipMemsetAsync(bufB, 0, (size_t)nN * 64 * 4, stream);
    k_scatter64<<<gEw, B, 0, stream>>>(bufA, bufB, S, R, nE);

    // layer 2: 64 -> 128 (fused relu + inv_r on input)
    k_lin2<<<gN, B, 0, stream>>>(bufB, W2, b2, inv_r, inv_s, bufA, nN);
    hipMemsetAsync(bufB, 0, (size_t)nN * 128 * 4, stream);
    k_scatter128<<<gEw, B, 0, stream>>>(bufA, bufB, S, R, nE);

    // layer 3: 128 -> 2
    k_lin3<<<gN, B, 0, stream>>>(bufB, W3, b3, inv_r, inv_s, bufC, nN);
    hipMemsetAsync(bufD, 0, (size_t)nN * 2 * 4, stream);
    k_scatter2<<<gE, B, 0, stream>>>(bufC, bufD, S, R, nE);

    // pooling
    hipMemsetAsync(d_out, 0, (size_t)out_size * 4, stream);
    k_pool<<<gN, B, 0, stream>>>(bufD, inv_r, batch, (float*)d_out, nN, out_size);
}

// Round 2
// 728.402 us; speedup vs baseline: 2.9947x; 2.9947x over previous
//
#include <hip/hip_runtime.h>
#include <hip/hip_bf16.h>
#include <cstddef>

// ---------------- degrees ----------------
__global__ void k_deg(const int* __restrict__ S, const int* __restrict__ R,
                      int* degS, int* degR, int nE) {
    int e = blockIdx.x * blockDim.x + threadIdx.x;
    if (e < nE) {
        atomicAdd(&degS[S[e]], 1);
        atomicAdd(&degR[R[e]], 1);
    }
}

// ---------------- CSR build: scan of degR ----------------
// per-block (1024 elems) exclusive scan into cur[], block totals into bsum[]
__global__ void k_scan_local(const int* __restrict__ deg, int* __restrict__ cur,
                             int* __restrict__ bsum, int nN) {
    __shared__ int sm[256];
    int base = blockIdx.x * 1024 + threadIdx.x * 4;
    int v[4];
    int t = 0;
#pragma unroll
    for (int i = 0; i < 4; i++) {
        int idx = base + i;
        v[i] = (idx < nN) ? deg[idx] : 0;
        t += v[i];
    }
    sm[threadIdx.x] = t;
    __syncthreads();
    for (int off = 1; off < 256; off <<= 1) {
        int y = (threadIdx.x >= off) ? sm[threadIdx.x - off] : 0;
        __syncthreads();
        sm[threadIdx.x] += y;
        __syncthreads();
    }
    int run = sm[threadIdx.x] - t;  // exclusive prefix of this thread's chunk
    if (threadIdx.x == 255) bsum[blockIdx.x] = sm[255];
#pragma unroll
    for (int i = 0; i < 4; i++) {
        int idx = base + i;
        if (idx < nN) cur[idx] = run;
        run += v[i];
    }
}

// exclusive scan of block sums (nB <= 256), single block
__global__ void k_scan_sums(int* bsum, int nB) {
    __shared__ int sm[256];
    int t = threadIdx.x;
    int orig = (t < nB) ? bsum[t] : 0;
    sm[t] = orig;
    __syncthreads();
    for (int off = 1; off < 256; off <<= 1) {
        int y = (t >= off) ? sm[t - off] : 0;
        __syncthreads();
        sm[t] += y;
        __syncthreads();
    }
    if (t < nB) bsum[t] = sm[t] - orig;
}

// add block prefix to cur; also compute inv_s/inv_r
__global__ void k_scan_add(int* __restrict__ cur, const int* __restrict__ bsum,
                           const int* __restrict__ degS, const int* __restrict__ degR,
                           float* __restrict__ inv_s, float* __restrict__ inv_r, int nN) {
    int n = blockIdx.x * blockDim.x + threadIdx.x;
    if (n >= nN) return;
    cur[n] += bsum[n >> 10];
    inv_s[n] = rsqrtf(fmaxf((float)degS[n], 1.0f));
    inv_r[n] = rsqrtf(fmaxf((float)degR[n], 1.0f));
}

// fill csr_src grouped by receiver; after this, cur[n] = end offset of node n
__global__ void k_fill(const int* __restrict__ S, const int* __restrict__ R,
                       int* __restrict__ cur, int* __restrict__ csr, int nE) {
    int e = blockIdx.x * blockDim.x + threadIdx.x;
    if (e >= nE) return;
    int pos = atomicAdd(&cur[R[e]], 1);
    csr[pos] = S[e];
}

// ---------------- layer 1 dense: x[N,9] @ W1[9,64] + b1, * inv_s ----------------
__global__ void k_lin1(const float* __restrict__ x, const float* __restrict__ W,
                       const float* __restrict__ b, const float* __restrict__ inv_s,
                       float* __restrict__ out, int nN) {
    __shared__ float Wl[9 * 64];
    __shared__ float bl[64];
    for (int i = threadIdx.x; i < 9 * 64; i += blockDim.x) Wl[i] = W[i];
    if (threadIdx.x < 64) bl[threadIdx.x] = b[threadIdx.x];
    __syncthreads();
    int n = blockIdx.x * blockDim.x + threadIdx.x;
    if (n >= nN) return;
    float xv[9];
#pragma unroll
    for (int k = 0; k < 9; k++) xv[k] = x[(size_t)n * 9 + k];
    float sc = inv_s[n];
    float* o = out + (size_t)n * 64;
#pragma unroll
    for (int c = 0; c < 4; c++) {
        float acc[16];
#pragma unroll
        for (int j = 0; j < 16; j++) acc[j] = bl[c * 16 + j];
#pragma unroll
        for (int k = 0; k < 9; k++) {
#pragma unroll
            for (int j = 0; j < 16; j++) acc[j] += xv[k] * Wl[k * 64 + c * 16 + j];
        }
#pragma unroll
        for (int q = 0; q < 4; q++) {
            float4 v = make_float4(acc[4 * q + 0] * sc, acc[4 * q + 1] * sc,
                                   acc[4 * q + 2] * sc, acc[4 * q + 3] * sc);
            *(float4*)(o + c * 16 + 4 * q) = v;
        }
    }
}

// ---------------- aggregation (gather, atomic-free): wave per node ----------------
// B[n,f] = relu(inv_r[n] * sum_{e: recv=n} A[src_e, f]),  F=64
__global__ void k_agg64(const float* __restrict__ A, float* __restrict__ B,
                        const int* __restrict__ csr, const int* __restrict__ cur,
                        const int* __restrict__ degR, const float* __restrict__ inv_r,
                        int nN) {
    int gid = blockIdx.x * blockDim.x + threadIdx.x;
    int n = gid >> 6;
    int lane = threadIdx.x & 63;
    if (n >= nN) return;
    int deg = degR[n];
    int st = cur[n] - deg;
    float s0 = 0.f, s1 = 0.f;
    int i = 0;
    for (; i + 2 <= deg; i += 2) {
        int a = csr[st + i];
        int b = csr[st + i + 1];
        s0 += A[(size_t)a * 64 + lane];
        s1 += A[(size_t)b * 64 + lane];
    }
    if (i < deg) s0 += A[(size_t)csr[st + i] * 64 + lane];
    B[(size_t)n * 64 + lane] = fmaxf((s0 + s1) * inv_r[n], 0.f);
}

// F=128 (float2 per lane)
__global__ void k_agg128(const float* __restrict__ A, float* __restrict__ B,
                         const int* __restrict__ csr, const int* __restrict__ cur,
                         const int* __restrict__ degR, const float* __restrict__ inv_r,
                         int nN) {
    int gid = blockIdx.x * blockDim.x + threadIdx.x;
    int n = gid >> 6;
    int lane = threadIdx.x & 63;
    if (n >= nN) return;
    int deg = degR[n];
    int st = cur[n] - deg;
    float2 s0 = make_float2(0.f, 0.f), s1 = make_float2(0.f, 0.f);
    int i = 0;
    for (; i + 2 <= deg; i += 2) {
        int a = csr[st + i];
        int b = csr[st + i + 1];
        float2 va = ((const float2*)(A + (size_t)a * 128))[lane];
        float2 vb = ((const float2*)(A + (size_t)b * 128))[lane];
        s0.x += va.x; s0.y += va.y;
        s1.x += vb.x; s1.y += vb.y;
    }
    if (i < deg) {
        float2 va = ((const float2*)(A + (size_t)csr[st + i] * 128))[lane];
        s0.x += va.x; s0.y += va.y;
    }
    float ir = inv_r[n];
    float2 r = make_float2(fmaxf((s0.x + s1.x) * ir, 0.f), fmaxf((s0.y + s1.y) * ir, 0.f));
    ((float2*)(B + (size_t)n * 128))[lane] = r;
}

// ---------------- layer 2 dense: in[N,64] @ W2[64,128] + b2, * inv_s ----------------
// (relu and inv_r already applied by k_agg64)
__global__ void k_lin2(const float* __restrict__ in, const float* __restrict__ W,
                       const float* __restrict__ b, const float* __restrict__ inv_s,
                       float* __restrict__ out, int nN) {
    __shared__ float Wl[64 * 128];  // 32 KB
    __shared__ float bl[128];
    for (int i = threadIdx.x; i < 64 * 128; i += blockDim.x) Wl[i] = W[i];
    for (int i = threadIdx.x; i < 128; i += blockDim.x) bl[i] = b[i];
    __syncthreads();
    int n = blockIdx.x * blockDim.x + threadIdx.x;
    if (n >= nN) return;
    float sc = inv_s[n];
    float xv[64];
    const float4* xin = (const float4*)(in + (size_t)n * 64);
#pragma unroll
    for (int k4 = 0; k4 < 16; k4++) {
        float4 v = xin[k4];
        xv[4 * k4 + 0] = v.x;
        xv[4 * k4 + 1] = v.y;
        xv[4 * k4 + 2] = v.z;
        xv[4 * k4 + 3] = v.w;
    }
    float* o = out + (size_t)n * 128;
#pragma unroll
    for (int c = 0; c < 8; c++) {
        float acc[16];
#pragma unroll
        for (int j = 0; j < 16; j++) acc[j] = bl[c * 16 + j];
#pragma unroll 8
        for (int k = 0; k < 64; k++) {
#pragma unroll
            for (int j = 0; j < 16; j++) acc[j] += xv[k] * Wl[k * 128 + c * 16 + j];
        }
#pragma unroll
        for (int q = 0; q < 4; q++) {
            float4 v = make_float4(acc[4 * q + 0] * sc, acc[4 * q + 1] * sc,
                                   acc[4 * q + 2] * sc, acc[4 * q + 3] * sc);
            *(float4*)(o + c * 16 + 4 * q) = v;
        }
    }
}

// ---------------- layer 3 dense: in[N,128] @ W3[128,2] + b3, * inv_s ----------------
// (relu and inv_r already applied by k_agg128)
__global__ void k_lin3(const float* __restrict__ in, const float* __restrict__ W,
                       const float* __restrict__ b, const float* __restrict__ inv_s,
                       float* __restrict__ out, int nN) {
    __shared__ float Wl[128 * 2];
    __shared__ float bl[2];
    for (int i = threadIdx.x; i < 256; i += blockDim.x) Wl[i] = W[i];
    if (threadIdx.x < 2) bl[threadIdx.x] = b[threadIdx.x];
    __syncthreads();
    int n = blockIdx.x * blockDim.x + threadIdx.x;
    if (n >= nN) return;
    float sc = inv_s[n];
    float acc0 = bl[0], acc1 = bl[1];
    const float4* xin = (const float4*)(in + (size_t)n * 128);
#pragma unroll 8
    for (int k4 = 0; k4 < 32; k4++) {
        float4 v = xin[k4];
        int k = 4 * k4;
        acc0 += v.x * Wl[(k + 0) * 2] + v.y * Wl[(k + 1) * 2] + v.z * Wl[(k + 2) * 2] + v.w * Wl[(k + 3) * 2];
        acc1 += v.x * Wl[(k + 0) * 2 + 1] + v.y * Wl[(k + 1) * 2 + 1] + v.z * Wl[(k + 2) * 2 + 1] + v.w * Wl[(k + 3) * 2 + 1];
    }
    *(float2*)(out + (size_t)n * 2) = make_float2(acc0 * sc, acc1 * sc);
}

// ---------------- fused layer-3 aggregation + graph pooling ----------------
// out[g,:] += sum over edges e with batch[R[e]]==g of inv_r[R[e]] * y3[S[e],:]
__global__ void k_pool3(const float* __restrict__ y3, const float* __restrict__ inv_r,
                        const int* __restrict__ S, const int* __restrict__ R,
                        const int* __restrict__ batch, float* out, int nE, int outSize) {
    __shared__ float sm[256];
    for (int i = threadIdx.x; i < 256; i += blockDim.x) sm[i] = 0.f;
    __syncthreads();
    for (int e = blockIdx.x * blockDim.x + threadIdx.x; e < nE; e += gridDim.x * blockDim.x) {
        int r = R[e];
        int s = S[e];
        float ir = inv_r[r];
        int g = batch[r];
        float2 v = ((const float2*)y3)[s];
        atomicAdd(&sm[2 * g + 0], v.x * ir);
        atomicAdd(&sm[2 * g + 1], v.y * ir);
    }
    __syncthreads();
    for (int i = threadIdx.x; i < outSize; i += blockDim.x) atomicAdd(&out[i], sm[i]);
}

extern "C" void kernel_launch(void* const* d_in, const int* in_sizes, int n_in,
                              void* d_out, int out_size, void* d_ws, size_t ws_size,
                              hipStream_t stream) {
    const float* x     = (const float*)d_in[0];
    const int*   S     = (const int*)d_in[1];
    const int*   R     = (const int*)d_in[2];
    const int*   batch = (const int*)d_in[3];
    const float* W1 = (const float*)d_in[5];
    const float* b1 = (const float*)d_in[6];
    const float* W2 = (const float*)d_in[7];
    const float* b2 = (const float*)d_in[8];
    const float* W3 = (const float*)d_in[9];
    const float* b3 = (const float*)d_in[10];

    int nN = in_sizes[0] / 9;
    int nE = in_sizes[1];

    char* ws = (char*)d_ws;
    int*   degS = (int*)ws;                         // nN
    int*   degR = degS + nN;                        // nN
    int*   cur  = degR + nN;                        // nN
    int*   bsum = cur + nN;                         // 256 (padded)
    float* inv_s = (float*)(bsum + 256);            // nN
    float* inv_r = inv_s + nN;                      // nN
    int*   csr   = (int*)(inv_r + nN);              // nE
    float* bufA  = (float*)(csr + nE);              // nN*128
    float* bufB  = bufA + (size_t)nN * 128;         // nN*128
    float* bufC  = bufA;                            // nN*2 (bufA dead by lin3)

    const int B = 256;
    int gN = (nN + B - 1) / B;
    int gE = (nE + B - 1) / B;
    int gW = (int)(((size_t)nN * 64 + B - 1) / B);  // wave-per-node grids
    int nScanBlocks = (nN + 1023) / 1024;           // must be <= 256

    // degrees + CSR (same adjacency for all layers)
    hipMemsetAsync(degS, 0, (size_t)2 * nN * 4, stream);
    k_deg<<<gE, B, 0, stream>>>(S, R, degS, degR, nE);
    k_scan_local<<<nScanBlocks, B, 0, stream>>>(degR, cur, bsum, nN);
    k_scan_sums<<<1, B, 0, stream>>>(bsum, nScanBlocks);
    k_scan_add<<<gN, B, 0, stream>>>(cur, bsum, degS, degR, inv_s, inv_r, nN);
    k_fill<<<gE, B, 0, stream>>>(S, R, cur, csr, nE);

    // layer 1: 9 -> 64
    k_lin1<<<gN, B, 0, stream>>>(x, W1, b1, inv_s, bufA, nN);
    k_agg64<<<gW, B, 0, stream>>>(bufA, bufB, csr, cur, degR, inv_r, nN);

    // layer 2: 64 -> 128
    k_lin2<<<gN, B, 0, stream>>>(bufB, W2, b2, inv_s, bufA, nN);
    k_agg128<<<gW, B, 0, stream>>>(bufA, bufB, csr, cur, degR, inv_r, nN);

    // layer 3: 128 -> 2 (+ fused aggregation & pooling)
    k_lin3<<<gN, B, 0, stream>>>(bufB, W3, b3, inv_s, bufC, nN);
    hipMemsetAsync(d_out, 0, (size_t)out_size * 4, stream);
    k_pool3<<<1024, B, 0, stream>>>(bufC, inv_r, S, R, batch, (float*)d_out, nE, out_size);
}

// Round 3
// 613.584 us; speedup vs baseline: 3.5551x; 1.1871x over previous
//
#include <hip/hip_runtime.h>
#include <hip/hip_bf16.h>
#include <cstddef>

// ---------------- degrees ----------------
__global__ void k_deg(const int* __restrict__ S, const int* __restrict__ R,
                      int* degS, int* degR, int nE) {
    int e = blockIdx.x * blockDim.x + threadIdx.x;
    if (e < nE) {
        atomicAdd(&degS[S[e]], 1);
        atomicAdd(&degR[R[e]], 1);
    }
}

// ---------------- CSR build: scan of degR ----------------
__global__ void k_scan_local(const int* __restrict__ deg, int* __restrict__ cur,
                             int* __restrict__ bsum, int nN) {
    __shared__ int sm[256];
    int base = blockIdx.x * 1024 + threadIdx.x * 4;
    int v[4];
    int t = 0;
#pragma unroll
    for (int i = 0; i < 4; i++) {
        int idx = base + i;
        v[i] = (idx < nN) ? deg[idx] : 0;
        t += v[i];
    }
    sm[threadIdx.x] = t;
    __syncthreads();
    for (int off = 1; off < 256; off <<= 1) {
        int y = (threadIdx.x >= off) ? sm[threadIdx.x - off] : 0;
        __syncthreads();
        sm[threadIdx.x] += y;
        __syncthreads();
    }
    int run = sm[threadIdx.x] - t;
    if (threadIdx.x == 255) bsum[blockIdx.x] = sm[255];
#pragma unroll
    for (int i = 0; i < 4; i++) {
        int idx = base + i;
        if (idx < nN) cur[idx] = run;
        run += v[i];
    }
}

__global__ void k_scan_sums(int* bsum, int nB) {
    __shared__ int sm[256];
    int t = threadIdx.x;
    int orig = (t < nB) ? bsum[t] : 0;
    sm[t] = orig;
    __syncthreads();
    for (int off = 1; off < 256; off <<= 1) {
        int y = (t >= off) ? sm[t - off] : 0;
        __syncthreads();
        sm[t] += y;
        __syncthreads();
    }
    if (t < nB) bsum[t] = sm[t] - orig;
}

__global__ void k_scan_add(int* __restrict__ cur, const int* __restrict__ bsum,
                           const int* __restrict__ degS, const int* __restrict__ degR,
                           float* __restrict__ inv_s, float* __restrict__ inv_r, int nN) {
    int n = blockIdx.x * blockDim.x + threadIdx.x;
    if (n >= nN) return;
    cur[n] += bsum[n >> 10];
    inv_s[n] = rsqrtf(fmaxf((float)degS[n], 1.0f));
    inv_r[n] = rsqrtf(fmaxf((float)degR[n], 1.0f));
}

__global__ void k_fill(const int* __restrict__ S, const int* __restrict__ R,
                       int* __restrict__ cur, int* __restrict__ csr, int nE) {
    int e = blockIdx.x * blockDim.x + threadIdx.x;
    if (e >= nE) return;
    int pos = atomicAdd(&cur[R[e]], 1);
    csr[pos] = S[e];
}

// ---------------- prep: xs16[n] = {x[n]*inv_s[n] (9), inv_s[n], 0 x6} ----------------
__global__ void k_prep(const float* __restrict__ x, const float* __restrict__ inv_s,
                       float* __restrict__ xs16, int nN) {
    int n = blockIdx.x * blockDim.x + threadIdx.x;
    if (n >= nN) return;
    float iv = inv_s[n];
    float v[9];
#pragma unroll
    for (int k = 0; k < 9; k++) v[k] = x[(size_t)n * 9 + k] * iv;
    float4* o = (float4*)(xs16 + (size_t)n * 16);
    o[0] = make_float4(v[0], v[1], v[2], v[3]);
    o[1] = make_float4(v[4], v[5], v[6], v[7]);
    o[2] = make_float4(v[8], iv, 0.f, 0.f);
    o[3] = make_float4(0.f, 0.f, 0.f, 0.f);
}

// ---------------- layer-1 aggregation: quarter-wave per node, width 16 ----------------
__global__ void k_agg16(const float* __restrict__ A, float* __restrict__ Z,
                        const int* __restrict__ csr, const int* __restrict__ cur,
                        const int* __restrict__ degR, int nN) {
    int gid = blockIdx.x * blockDim.x + threadIdx.x;
    int n = gid >> 4;
    int f = threadIdx.x & 15;
    if (n >= nN) return;
    int deg = degR[n];
    int st = cur[n] - deg;
    float s0 = 0.f, s1 = 0.f;
    int i = 0;
    for (; i + 2 <= deg; i += 2) {
        int a = csr[st + i];
        int b = csr[st + i + 1];
        s0 += A[(size_t)a * 16 + f];
        s1 += A[(size_t)b * 16 + f];
    }
    if (i < deg) s0 += A[(size_t)csr[st + i] * 16 + f];
    Z[(size_t)n * 16 + f] = s0 + s1;
}

// ---------------- layer 1 dense: h1s = relu(inv_r*(z16@W1 + w*b1)) * inv_s ----------------
__global__ void k_lin1n(const float* __restrict__ Z, const float* __restrict__ W,
                        const float* __restrict__ b, const float* __restrict__ inv_r,
                        const float* __restrict__ inv_s, float* __restrict__ out,
                        float* __restrict__ warr, int nN) {
    __shared__ float Wl[9 * 64];
    __shared__ float bl[64];
    for (int i = threadIdx.x; i < 9 * 64; i += blockDim.x) Wl[i] = W[i];
    if (threadIdx.x < 64) bl[threadIdx.x] = b[threadIdx.x];
    __syncthreads();
    int n = blockIdx.x * blockDim.x + threadIdx.x;
    if (n >= nN) return;
    const float4* zi = (const float4*)(Z + (size_t)n * 16);
    float4 r0 = zi[0], r1 = zi[1], r2 = zi[2];
    float xv[9] = {r0.x, r0.y, r0.z, r0.w, r1.x, r1.y, r1.z, r1.w, r2.x};
    float w = r2.y;
    warr[n] = w;
    float ir = inv_r[n];
    float is = inv_s[n];
    float* o = out + (size_t)n * 64;
#pragma unroll
    for (int c = 0; c < 4; c++) {
        float acc[16];
#pragma unroll
        for (int j = 0; j < 16; j++) acc[j] = w * bl[c * 16 + j];
#pragma unroll
        for (int k = 0; k < 9; k++) {
#pragma unroll
            for (int j = 0; j < 16; j++) acc[j] += xv[k] * Wl[k * 64 + c * 16 + j];
        }
#pragma unroll
        for (int q = 0; q < 4; q++) {
            float4 v = make_float4(fmaxf(acc[4 * q + 0] * ir, 0.f) * is,
                                   fmaxf(acc[4 * q + 1] * ir, 0.f) * is,
                                   fmaxf(acc[4 * q + 2] * ir, 0.f) * is,
                                   fmaxf(acc[4 * q + 3] * ir, 0.f) * is);
            *(float4*)(o + c * 16 + 4 * q) = v;
        }
    }
}

// ---------------- layer-2 aggregation: plain sum, wave per node, width 64 ----------------
__global__ void k_aggsum64(const float* __restrict__ A, float* __restrict__ Z,
                           const int* __restrict__ csr, const int* __restrict__ cur,
                           const int* __restrict__ degR, int nN) {
    int gid = blockIdx.x * blockDim.x + threadIdx.x;
    int n = gid >> 6;
    int lane = threadIdx.x & 63;
    if (n >= nN) return;
    int deg = degR[n];
    int st = cur[n] - deg;
    float s0 = 0.f, s1 = 0.f;
    int i = 0;
    for (; i + 2 <= deg; i += 2) {
        int a = csr[st + i];
        int b = csr[st + i + 1];
        s0 += A[(size_t)a * 64 + lane];
        s1 += A[(size_t)b * 64 + lane];
    }
    if (i < deg) s0 += A[(size_t)csr[st + i] * 64 + lane];
    Z[(size_t)n * 64 + lane] = s0 + s1;
}

// ---------------- layer 2 dense (tiled, no spills) ----------------
// h2s = relu(inv_r*(z64@W2 + w*b2)) * inv_s
// block = 32 nodes x 8 col-tiles; W2 in LDS q-interleaved (bank-conflict-free)
__global__ void k_lin2t(const float* __restrict__ Z, const float* __restrict__ W,
                        const float* __restrict__ b, const float* __restrict__ inv_r,
                        const float* __restrict__ inv_s, const float* __restrict__ warr,
                        float* __restrict__ out, int nN) {
    __shared__ float Wl[64 * 128];       // element (k, c*16+q*4+j) at k*128 + q*32 + c*4 + j
    __shared__ float Xl[32 * 68];        // padded stride 68
    __shared__ float bl[128];
    // load W2 with q-interleave: global float4 m -> k=m>>5, c=(m&31)>>2, q=m&3
    for (int m = threadIdx.x; m < 2048; m += blockDim.x) {
        float4 wv = ((const float4*)W)[m];
        int k = m >> 5, rem = m & 31, c = rem >> 2, q = rem & 3;
        *(float4*)(Wl + k * 128 + q * 32 + c * 4) = wv;
    }
    for (int i = threadIdx.x; i < 128; i += blockDim.x) bl[i] = b[i];
    int nb = blockIdx.x * 32;
    // stage X tile: 32 nodes x 16 float4
    for (int idx = threadIdx.x; idx < 32 * 16; idx += blockDim.x) {
        int node = idx >> 4, k4 = idx & 15;
        float4 v = make_float4(0.f, 0.f, 0.f, 0.f);
        if (nb + node < nN) v = ((const float4*)(Z + (size_t)(nb + node) * 64))[k4];
        Xl[node * 68 + k4 * 4 + 0] = v.x;
        Xl[node * 68 + k4 * 4 + 1] = v.y;
        Xl[node * 68 + k4 * 4 + 2] = v.z;
        Xl[node * 68 + k4 * 4 + 3] = v.w;
    }
    __syncthreads();
    int nl = threadIdx.x >> 3;
    int c = threadIdx.x & 7;
    int n = nb + nl;
    if (n >= nN) return;
    float w = warr[n];
    float acc[16];
#pragma unroll
    for (int q = 0; q < 4; q++) {
#pragma unroll
        for (int j = 0; j < 4; j++) acc[q * 4 + j] = w * bl[c * 16 + q * 4 + j];
    }
#pragma unroll 8
    for (int k = 0; k < 64; k++) {
        float xv = Xl[nl * 68 + k];
        const float* wr = Wl + k * 128 + c * 4;
#pragma unroll
        for (int q = 0; q < 4; q++) {
            float4 wv = *(const float4*)(wr + q * 32);
            acc[q * 4 + 0] += xv * wv.x;
            acc[q * 4 + 1] += xv * wv.y;
            acc[q * 4 + 2] += xv * wv.z;
            acc[q * 4 + 3] += xv * wv.w;
        }
    }
    float ir = inv_r[n];
    float is = inv_s[n];
    float* o = out + (size_t)n * 128 + c * 16;
#pragma unroll
    for (int q = 0; q < 4; q++) {
        float4 v = make_float4(fmaxf(acc[q * 4 + 0] * ir, 0.f) * is,
                               fmaxf(acc[q * 4 + 1] * ir, 0.f) * is,
                               fmaxf(acc[q * 4 + 2] * ir, 0.f) * is,
                               fmaxf(acc[q * 4 + 3] * ir, 0.f) * is);
        *(float4*)(o + q * 4) = v;
    }
}

// ---------------- layer 3 dense: t = h2s @ W3 (no bias/scale here) ----------------
__global__ void k_lin3t(const float* __restrict__ in, const float* __restrict__ W,
                        float* __restrict__ out, int nN) {
    __shared__ float Wl[128 * 2];
    for (int i = threadIdx.x; i < 256; i += blockDim.x) Wl[i] = W[i];
    __syncthreads();
    int n = blockIdx.x * blockDim.x + threadIdx.x;
    if (n >= nN) return;
    float acc0 = 0.f, acc1 = 0.f;
    const float4* xin = (const float4*)(in + (size_t)n * 128);
#pragma unroll 8
    for (int k4 = 0; k4 < 32; k4++) {
        float4 v = xin[k4];
        int k = 4 * k4;
        acc0 += v.x * Wl[(k + 0) * 2] + v.y * Wl[(k + 1) * 2] + v.z * Wl[(k + 2) * 2] + v.w * Wl[(k + 3) * 2];
        acc1 += v.x * Wl[(k + 0) * 2 + 1] + v.y * Wl[(k + 1) * 2 + 1] + v.z * Wl[(k + 2) * 2 + 1] + v.w * Wl[(k + 3) * 2 + 1];
    }
    *(float2*)(out + (size_t)n * 2) = make_float2(acc0, acc1);
}

// ---------------- fused layer-3 aggregation + bias + pooling ----------------
// edge term: out[batch[r]] += inv_r[r] * t[s];  node term: out[batch[n]] += inv_r[n]*w[n]*b3
__global__ void k_poolf(const float* __restrict__ t, const float* __restrict__ inv_r,
                        const float* __restrict__ warr, const float* __restrict__ b3,
                        const int* __restrict__ S, const int* __restrict__ R,
                        const int* __restrict__ batch, float* out,
                        int nE, int nN, int outSize) {
    __shared__ float sm[256];
    for (int i = threadIdx.x; i < 256; i += blockDim.x) sm[i] = 0.f;
    __syncthreads();
    float b30 = b3[0], b31 = b3[1];
    for (int e = blockIdx.x * blockDim.x + threadIdx.x; e < nE; e += gridDim.x * blockDim.x) {
        int r = R[e];
        int s = S[e];
        float ir = inv_r[r];
        int g = batch[r];
        float2 v = ((const float2*)t)[s];
        atomicAdd(&sm[2 * g + 0], v.x * ir);
        atomicAdd(&sm[2 * g + 1], v.y * ir);
    }
    for (int n = blockIdx.x * blockDim.x + threadIdx.x; n < nN; n += gridDim.x * blockDim.x) {
        float c = inv_r[n] * warr[n];
        int g = batch[n];
        atomicAdd(&sm[2 * g + 0], c * b30);
        atomicAdd(&sm[2 * g + 1], c * b31);
    }
    __syncthreads();
    for (int i = threadIdx.x; i < outSize; i += blockDim.x) atomicAdd(&out[i], sm[i]);
}

extern "C" void kernel_launch(void* const* d_in, const int* in_sizes, int n_in,
                              void* d_out, int out_size, void* d_ws, size_t ws_size,
                              hipStream_t stream) {
    const float* x     = (const float*)d_in[0];
    const int*   S     = (const int*)d_in[1];
    const int*   R     = (const int*)d_in[2];
    const int*   batch = (const int*)d_in[3];
    const float* W1 = (const float*)d_in[5];
    const float* b1 = (const float*)d_in[6];
    const float* W2 = (const float*)d_in[7];
    const float* b2 = (const float*)d_in[8];
    const float* W3 = (const float*)d_in[9];
    const float* b3 = (const float*)d_in[10];

    int nN = in_sizes[0] / 9;
    int nE = in_sizes[1];

    char* ws = (char*)d_ws;
    int*   degS = (int*)ws;                          // nN
    int*   degR = degS + nN;                         // nN
    int*   cur  = degR + nN;                         // nN
    int*   bsum = cur + nN;                          // 256
    float* inv_s = (float*)(bsum + 256);             // nN
    float* inv_r = inv_s + nN;                       // nN
    float* warr  = inv_r + nN;                       // nN
    int*   csr   = (int*)(warr + nN);                // nE
    float* xs16  = (float*)(csr + nE);               // nN*16
    float* regA  = xs16 + (size_t)nN * 16;           // nN*128 region
    float* z16   = regA;                             // nN*16 (dead after lin1n)
    float* h1s   = regA + (size_t)nN * 16;           // nN*64 (dead after aggsum64)
    float* h2s   = regA;                             // nN*128 (overwrites z16+h1s, both dead)
    float* regB  = regA + (size_t)nN * 128;          // nN*64 region
    float* z64   = regB;                             // nN*64 (dead after lin2t)
    float* t     = regB;                             // nN*2 (after lin2t)

    const int B = 256;
    int gN = (nN + B - 1) / B;
    int gE = (nE + B - 1) / B;
    int gQ = (int)(((size_t)nN * 16 + B - 1) / B);
    int gW = (int)(((size_t)nN * 64 + B - 1) / B);
    int nScanBlocks = (nN + 1023) / 1024;

    // degrees + CSR (adjacency identical across layers)
    hipMemsetAsync(degS, 0, (size_t)2 * nN * 4, stream);
    k_deg<<<gE, B, 0, stream>>>(S, R, degS, degR, nE);
    k_scan_local<<<nScanBlocks, B, 0, stream>>>(degR, cur, bsum, nN);
    k_scan_sums<<<1, B, 0, stream>>>(bsum, nScanBlocks);
    k_scan_add<<<gN, B, 0, stream>>>(cur, bsum, degS, degR, inv_s, inv_r, nN);
    k_prep<<<gN, B, 0, stream>>>(x, inv_s, xs16, nN);
    k_fill<<<gE, B, 0, stream>>>(S, R, cur, csr, nE);

    // layer 1: aggregate at width 16, then 9->64 dense
    k_agg16<<<gQ, B, 0, stream>>>(xs16, z16, csr, cur, degR, nN);
    k_lin1n<<<gN, B, 0, stream>>>(z16, W1, b1, inv_r, inv_s, h1s, warr, nN);

    // layer 2: aggregate at width 64, then 64->128 dense (tiled)
    k_aggsum64<<<gW, B, 0, stream>>>(h1s, z64, csr, cur, degR, nN);
    k_lin2t<<<(nN + 31) / 32, B, 0, stream>>>(z64, W2, b2, inv_r, inv_s, warr, h2s, nN);

    // layer 3: transform 128->2, then fused aggregation + bias + pooling
    k_lin3t<<<gN, B, 0, stream>>>(h2s, W3, t, nN);
    hipMemsetAsync(d_out, 0, (size_t)out_size * 4, stream);
    k_poolf<<<1024, B, 0, stream>>>(t, inv_r, warr, b3, S, R, batch, (float*)d_out, nE, nN, out_size);
}

// Round 4
// 436.514 us; speedup vs baseline: 4.9972x; 1.4056x over previous
//
#include <hip/hip_runtime.h>
#include <hip/hip_bf16.h>
#include <cstddef>

#define BCAP 12288  // per-bucket capacity; mean ~8163, +6 sigma ~8700 << 12288

// ---------------- pass 1: bucket edges by receiver (bucket = r>>9) ----------------
// entry = (r&511)<<23 | s   (needs nN <= 2^23)
__global__ void k_bucketR(const int* __restrict__ S, const int* __restrict__ R,
                          unsigned* __restrict__ buf, int* __restrict__ gCnt,
                          int nE, int nB) {
    __shared__ int hist[256];
    __shared__ int base[256];
    for (int i = threadIdx.x; i < 256; i += blockDim.x) hist[i] = 0;
    __syncthreads();
    int chunk = (nE + gridDim.x - 1) / gridDim.x;
    int e0 = blockIdx.x * chunk;
    int e1 = min(e0 + chunk, nE);
    for (int e = e0 + threadIdx.x; e < e1; e += blockDim.x)
        atomicAdd(&hist[R[e] >> 9], 1);
    __syncthreads();
    if (threadIdx.x < nB) {
        int c = hist[threadIdx.x];
        base[threadIdx.x] = c ? atomicAdd(&gCnt[threadIdx.x], c) : 0;
    }
    __syncthreads();
    for (int i = threadIdx.x; i < 256; i += blockDim.x) hist[i] = 0;  // reuse as cursor
    __syncthreads();
    for (int e = e0 + threadIdx.x; e < e1; e += blockDim.x) {
        int r = R[e], s = S[e];
        int b = r >> 9;
        int slot = base[b] + atomicAdd(&hist[b], 1);
        if (slot < BCAP)
            buf[(size_t)b * BCAP + slot] = ((unsigned)(r & 511) << 23) | (unsigned)s;
    }
}

// bucket senders (value only, u16 local id)
__global__ void k_bucketS(const int* __restrict__ S, unsigned short* __restrict__ buf,
                          int* __restrict__ gCnt, int nE, int nB) {
    __shared__ int hist[256];
    __shared__ int base[256];
    for (int i = threadIdx.x; i < 256; i += blockDim.x) hist[i] = 0;
    __syncthreads();
    int chunk = (nE + gridDim.x - 1) / gridDim.x;
    int e0 = blockIdx.x * chunk;
    int e1 = min(e0 + chunk, nE);
    for (int e = e0 + threadIdx.x; e < e1; e += blockDim.x)
        atomicAdd(&hist[S[e] >> 9], 1);
    __syncthreads();
    if (threadIdx.x < nB) {
        int c = hist[threadIdx.x];
        base[threadIdx.x] = c ? atomicAdd(&gCnt[threadIdx.x], c) : 0;
    }
    __syncthreads();
    for (int i = threadIdx.x; i < 256; i += blockDim.x) hist[i] = 0;
    __syncthreads();
    for (int e = e0 + threadIdx.x; e < e1; e += blockDim.x) {
        int s = S[e];
        int b = s >> 9;
        int slot = base[b] + atomicAdd(&hist[b], 1);
        if (slot < BCAP)
            buf[(size_t)b * BCAP + slot] = (unsigned short)(s & 511);
    }
}

// exclusive scan of bucket counts (nB <= 256) -> edge base per bucket
__global__ void k_gbase(const int* __restrict__ gCnt, int* __restrict__ gBase, int nB) {
    __shared__ int sm[256];
    int t = threadIdx.x;
    int v = (t < nB) ? gCnt[t] : 0;
    sm[t] = v;
    __syncthreads();
    for (int off = 1; off < 256; off <<= 1) {
        int y = (t >= off) ? sm[t - off] : 0;
        __syncthreads();
        sm[t] += y;
        __syncthreads();
    }
    if (t < nB) gBase[t] = sm[t] - v;
}

// ---------------- pass 2: per-bucket exact CSR (coalesced outputs) ----------------
__global__ void k_pass2R(const unsigned* __restrict__ bufR, const int* __restrict__ gCnt,
                         const int* __restrict__ gBase, int* __restrict__ csr,
                         int* __restrict__ cur, int* __restrict__ degR,
                         float* __restrict__ inv_r, int nN) {
    __shared__ int hist[512];
    __shared__ int incl[512];
    __shared__ int curs[512];
    __shared__ int sm[256];
    int b = blockIdx.x;
    int cnt = gCnt[b];
    int gb = gBase[b];
    const unsigned* buf = bufR + (size_t)b * BCAP;
    for (int i = threadIdx.x; i < 512; i += blockDim.x) { hist[i] = 0; curs[i] = 0; }
    __syncthreads();
    for (int i = threadIdx.x; i < cnt; i += blockDim.x)
        atomicAdd(&hist[buf[i] >> 23], 1);
    __syncthreads();
    // inclusive scan over 512 bins (pairwise + Hillis-Steele on 256)
    int t = threadIdx.x;
    int a0 = hist[2 * t], a1 = hist[2 * t + 1];
    int ps = a0 + a1;
    sm[t] = ps;
    __syncthreads();
    for (int off = 1; off < 256; off <<= 1) {
        int y = (t >= off) ? sm[t - off] : 0;
        __syncthreads();
        sm[t] += y;
        __syncthreads();
    }
    int ex = sm[t] - ps;
    incl[2 * t] = ex + a0;
    incl[2 * t + 1] = ex + a0 + a1;
    __syncthreads();
    int n0 = b << 9;
    for (int i = threadIdx.x; i < 512; i += blockDim.x) {
        int n = n0 + i;
        if (n < nN) {
            int d = hist[i];
            degR[n] = d;
            cur[n] = gb + incl[i];  // end offset (agg kernels use cur-deg)
            inv_r[n] = rsqrtf(fmaxf((float)d, 1.f));
        }
    }
    for (int i = threadIdx.x; i < cnt; i += blockDim.x) {
        unsigned p = buf[i];
        int rl = p >> 23;
        int s = p & 0x7FFFFF;
        int pos = gb + (incl[rl] - hist[rl]) + atomicAdd(&curs[rl], 1);
        csr[pos] = s;  // writes land in one contiguous ~32KB window per block
    }
}

__global__ void k_pass2S(const unsigned short* __restrict__ bufS, const int* __restrict__ gCnt,
                         float* __restrict__ inv_s, int nN) {
    __shared__ int hist[512];
    int b = blockIdx.x;
    int cnt = gCnt[b];
    const unsigned short* buf = bufS + (size_t)b * BCAP;
    for (int i = threadIdx.x; i < 512; i += blockDim.x) hist[i] = 0;
    __syncthreads();
    for (int i = threadIdx.x; i < cnt; i += blockDim.x)
        atomicAdd(&hist[buf[i]], 1);
    __syncthreads();
    int n0 = b << 9;
    for (int i = threadIdx.x; i < 512; i += blockDim.x) {
        int n = n0 + i;
        if (n < nN) inv_s[n] = rsqrtf(fmaxf((float)hist[i], 1.f));
    }
}

// ---------------- prep: xs16[n] = {x[n]*inv_s[n] (9), inv_s[n], 0 x6} ----------------
__global__ void k_prep(const float* __restrict__ x, const float* __restrict__ inv_s,
                       float* __restrict__ xs16, int nN) {
    int n = blockIdx.x * blockDim.x + threadIdx.x;
    if (n >= nN) return;
    float iv = inv_s[n];
    float v[9];
#pragma unroll
    for (int k = 0; k < 9; k++) v[k] = x[(size_t)n * 9 + k] * iv;
    float4* o = (float4*)(xs16 + (size_t)n * 16);
    o[0] = make_float4(v[0], v[1], v[2], v[3]);
    o[1] = make_float4(v[4], v[5], v[6], v[7]);
    o[2] = make_float4(v[8], iv, 0.f, 0.f);
    o[3] = make_float4(0.f, 0.f, 0.f, 0.f);
}

// ---------------- layer-1 aggregation: quarter-wave per node, width 16 ----------------
__global__ void k_agg16(const float* __restrict__ A, float* __restrict__ Z,
                        const int* __restrict__ csr, const int* __restrict__ cur,
                        const int* __restrict__ degR, int nN) {
    int gid = blockIdx.x * blockDim.x + threadIdx.x;
    int n = gid >> 4;
    int f = threadIdx.x & 15;
    if (n >= nN) return;
    int deg = degR[n];
    int st = cur[n] - deg;
    float s0 = 0.f, s1 = 0.f;
    int i = 0;
    for (; i + 2 <= deg; i += 2) {
        int a = csr[st + i];
        int b = csr[st + i + 1];
        s0 += A[(size_t)a * 16 + f];
        s1 += A[(size_t)b * 16 + f];
    }
    if (i < deg) s0 += A[(size_t)csr[st + i] * 16 + f];
    Z[(size_t)n * 16 + f] = s0 + s1;
}

// ---------------- layer 1 dense: h1s = relu(inv_r*(z16@W1 + w*b1)) * inv_s ----------------
__global__ void k_lin1n(const float* __restrict__ Z, const float* __restrict__ W,
                        const float* __restrict__ b, const float* __restrict__ inv_r,
                        const float* __restrict__ inv_s, float* __restrict__ out,
                        float* __restrict__ warr, int nN) {
    __shared__ float Wl[9 * 64];
    __shared__ float bl[64];
    for (int i = threadIdx.x; i < 9 * 64; i += blockDim.x) Wl[i] = W[i];
    if (threadIdx.x < 64) bl[threadIdx.x] = b[threadIdx.x];
    __syncthreads();
    int n = blockIdx.x * blockDim.x + threadIdx.x;
    if (n >= nN) return;
    const float4* zi = (const float4*)(Z + (size_t)n * 16);
    float4 r0 = zi[0], r1 = zi[1], r2 = zi[2];
    float xv[9] = {r0.x, r0.y, r0.z, r0.w, r1.x, r1.y, r1.z, r1.w, r2.x};
    float w = r2.y;
    warr[n] = w;
    float ir = inv_r[n];
    float is = inv_s[n];
    float* o = out + (size_t)n * 64;
#pragma unroll
    for (int c = 0; c < 4; c++) {
        float acc[16];
#pragma unroll
        for (int j = 0; j < 16; j++) acc[j] = w * bl[c * 16 + j];
#pragma unroll
        for (int k = 0; k < 9; k++) {
#pragma unroll
            for (int j = 0; j < 16; j++) acc[j] += xv[k] * Wl[k * 64 + c * 16 + j];
        }
#pragma unroll
        for (int q = 0; q < 4; q++) {
            float4 v = make_float4(fmaxf(acc[4 * q + 0] * ir, 0.f) * is,
                                   fmaxf(acc[4 * q + 1] * ir, 0.f) * is,
                                   fmaxf(acc[4 * q + 2] * ir, 0.f) * is,
                                   fmaxf(acc[4 * q + 3] * ir, 0.f) * is);
            *(float4*)(o + c * 16 + 4 * q) = v;
        }
    }
}

// ---------------- layer-2 aggregation: plain sum, wave per node, width 64 ----------------
__global__ void k_aggsum64(const float* __restrict__ A, float* __restrict__ Z,
                           const int* __restrict__ csr, const int* __restrict__ cur,
                           const int* __restrict__ degR, int nN) {
    int gid = blockIdx.x * blockDim.x + threadIdx.x;
    int n = gid >> 6;
    int lane = threadIdx.x & 63;
    if (n >= nN) return;
    int deg = degR[n];
    int st = cur[n] - deg;
    float s0 = 0.f, s1 = 0.f;
    int i = 0;
    for (; i + 2 <= deg; i += 2) {
        int a = csr[st + i];
        int b = csr[st + i + 1];
        s0 += A[(size_t)a * 64 + lane];
        s1 += A[(size_t)b * 64 + lane];
    }
    if (i < deg) s0 += A[(size_t)csr[st + i] * 64 + lane];
    Z[(size_t)n * 64 + lane] = s0 + s1;
}

// ---------------- layer 2 dense (tiled): h2s = relu(inv_r*(z64@W2 + w*b2)) * inv_s ----------------
__global__ void k_lin2t(const float* __restrict__ Z, const float* __restrict__ W,
                        const float* __restrict__ b, const float* __restrict__ inv_r,
                        const float* __restrict__ inv_s, const float* __restrict__ warr,
                        float* __restrict__ out, int nN) {
    __shared__ float Wl[64 * 128];       // element (k, c*16+q*4+j) at k*128 + q*32 + c*4 + j
    __shared__ float Xl[32 * 68];
    __shared__ float bl[128];
    for (int m = threadIdx.x; m < 2048; m += blockDim.x) {
        float4 wv = ((const float4*)W)[m];
        int k = m >> 5, rem = m & 31, c = rem >> 2, q = rem & 3;
        *(float4*)(Wl + k * 128 + q * 32 + c * 4) = wv;
    }
    for (int i = threadIdx.x; i < 128; i += blockDim.x) bl[i] = b[i];
    int nb = blockIdx.x * 32;
    for (int idx = threadIdx.x; idx < 32 * 16; idx += blockDim.x) {
        int node = idx >> 4, k4 = idx & 15;
        float4 v = make_float4(0.f, 0.f, 0.f, 0.f);
        if (nb + node < nN) v = ((const float4*)(Z + (size_t)(nb + node) * 64))[k4];
        Xl[node * 68 + k4 * 4 + 0] = v.x;
        Xl[node * 68 + k4 * 4 + 1] = v.y;
        Xl[node * 68 + k4 * 4 + 2] = v.z;
        Xl[node * 68 + k4 * 4 + 3] = v.w;
    }
    __syncthreads();
    int nl = threadIdx.x >> 3;
    int c = threadIdx.x & 7;
    int n = nb + nl;
    if (n >= nN) return;
    float w = warr[n];
    float acc[16];
#pragma unroll
    for (int q = 0; q < 4; q++)
#pragma unroll
        for (int j = 0; j < 4; j++) acc[q * 4 + j] = w * bl[c * 16 + q * 4 + j];
#pragma unroll 8
    for (int k = 0; k < 64; k++) {
        float xv = Xl[nl * 68 + k];
        const float* wr = Wl + k * 128 + c * 4;
#pragma unroll
        for (int q = 0; q < 4; q++) {
            float4 wv = *(const float4*)(wr + q * 32);
            acc[q * 4 + 0] += xv * wv.x;
            acc[q * 4 + 1] += xv * wv.y;
            acc[q * 4 + 2] += xv * wv.z;
            acc[q * 4 + 3] += xv * wv.w;
        }
    }
    float ir = inv_r[n];
    float is = inv_s[n];
    float* o = out + (size_t)n * 128 + c * 16;
#pragma unroll
    for (int q = 0; q < 4; q++) {
        float4 v = make_float4(fmaxf(acc[q * 4 + 0] * ir, 0.f) * is,
                               fmaxf(acc[q * 4 + 1] * ir, 0.f) * is,
                               fmaxf(acc[q * 4 + 2] * ir, 0.f) * is,
                               fmaxf(acc[q * 4 + 3] * ir, 0.f) * is);
        *(float4*)(o + q * 4) = v;
    }
}

// ---------------- layer 3 dense: t = h2s @ W3 ----------------
__global__ void k_lin3t(const float* __restrict__ in, const float* __restrict__ W,
                        float* __restrict__ out, int nN) {
    __shared__ float Wl[128 * 2];
    for (int i = threadIdx.x; i < 256; i += blockDim.x) Wl[i] = W[i];
    __syncthreads();
    int n = blockIdx.x * blockDim.x + threadIdx.x;
    if (n >= nN) return;
    float acc0 = 0.f, acc1 = 0.f;
    const float4* xin = (const float4*)(in + (size_t)n * 128);
#pragma unroll 8
    for (int k4 = 0; k4 < 32; k4++) {
        float4 v = xin[k4];
        int k = 4 * k4;
        acc0 += v.x * Wl[(k + 0) * 2] + v.y * Wl[(k + 1) * 2] + v.z * Wl[(k + 2) * 2] + v.w * Wl[(k + 3) * 2];
        acc1 += v.x * Wl[(k + 0) * 2 + 1] + v.y * Wl[(k + 1) * 2 + 1] + v.z * Wl[(k + 2) * 2 + 1] + v.w * Wl[(k + 3) * 2 + 1];
    }
    *(float2*)(out + (size_t)n * 2) = make_float2(acc0, acc1);
}

// ---------------- fused layer-3 aggregation + bias + pooling ----------------
__global__ void k_poolf(const float* __restrict__ t, const float* __restrict__ inv_r,
                        const float* __restrict__ warr, const float* __restrict__ b3,
                        const int* __restrict__ S, const int* __restrict__ R,
                        const int* __restrict__ batch, float* out,
                        int nE, int nN, int outSize) {
    __shared__ float sm[256];
    for (int i = threadIdx.x; i < 256; i += blockDim.x) sm[i] = 0.f;
    __syncthreads();
    float b30 = b3[0], b31 = b3[1];
    for (int e = blockIdx.x * blockDim.x + threadIdx.x; e < nE; e += gridDim.x * blockDim.x) {
        int r = R[e];
        int s = S[e];
        float ir = inv_r[r];
        int g = batch[r];
        float2 v = ((const float2*)t)[s];
        atomicAdd(&sm[2 * g + 0], v.x * ir);
        atomicAdd(&sm[2 * g + 1], v.y * ir);
    }
    for (int n = blockIdx.x * blockDim.x + threadIdx.x; n < nN; n += gridDim.x * blockDim.x) {
        float c = inv_r[n] * warr[n];
        int g = batch[n];
        atomicAdd(&sm[2 * g + 0], c * b30);
        atomicAdd(&sm[2 * g + 1], c * b31);
    }
    __syncthreads();
    for (int i = threadIdx.x; i < outSize; i += blockDim.x) atomicAdd(&out[i], sm[i]);
}

extern "C" void kernel_launch(void* const* d_in, const int* in_sizes, int n_in,
                              void* d_out, int out_size, void* d_ws, size_t ws_size,
                              hipStream_t stream) {
    const float* x     = (const float*)d_in[0];
    const int*   S     = (const int*)d_in[1];
    const int*   R     = (const int*)d_in[2];
    const int*   batch = (const int*)d_in[3];
    const float* W1 = (const float*)d_in[5];
    const float* b1 = (const float*)d_in[6];
    const float* W2 = (const float*)d_in[7];
    const float* b2 = (const float*)d_in[8];
    const float* W3 = (const float*)d_in[9];
    const float* b3 = (const float*)d_in[10];

    int nN = in_sizes[0] / 9;
    int nE = in_sizes[1];
    int nB = (nN + 511) / 512;  // receiver/sender buckets of 512 nodes; requires nB <= 256

    char* ws = (char*)d_ws;
    int*   cur   = (int*)ws;                         // nN
    int*   degR  = cur + nN;                         // nN
    float* inv_s = (float*)(degR + nN);              // nN
    float* inv_r = inv_s + nN;                       // nN
    float* warr  = inv_r + nN;                       // nN
    int*   gCntR = (int*)(warr + nN);                // 256
    int*   gCntS = gCntR + 256;                      // 256
    int*   gBase = gCntS + 256;                      // 256
    int*   csr   = gBase + 256;                      // nE
    float* xs16  = (float*)(csr + nE);               // nN*16
    float* regA  = xs16 + (size_t)nN * 16;           // nN*128 region
    // bucket buffers alias regA (dead before k_agg16 writes z16)
    unsigned*       bufR = (unsigned*)regA;                  // 256*BCAP u32 = 12.6 MB
    unsigned short* bufS = (unsigned short*)(bufR + 256 * BCAP);  // 6.3 MB
    float* z16   = regA;                             // nN*16 (after build)
    float* h1s   = regA + (size_t)nN * 16;           // nN*64
    float* h2s   = regA;                             // nN*128 (z16+h1s dead)
    float* regB  = regA + (size_t)nN * 128;          // nN*64 region
    float* z64   = regB;
    float* t     = regB;                             // nN*2 (z64 dead after lin2t)

    const int B = 256;
    int gN = (nN + B - 1) / B;
    int gQ = (int)(((size_t)nN * 16 + B - 1) / B);
    int gW = (int)(((size_t)nN * 64 + B - 1) / B);

    // ---- CSR + degrees via bucket sort (no per-edge global atomics) ----
    hipMemsetAsync(gCntR, 0, 768 * 4, stream);
    k_bucketR<<<256, B, 0, stream>>>(S, R, bufR, gCntR, nE, nB);
    k_bucketS<<<256, B, 0, stream>>>(S, bufS, gCntS, nE, nB);
    k_gbase<<<1, B, 0, stream>>>(gCntR, gBase, nB);
    k_pass2R<<<nB, B, 0, stream>>>(bufR, gCntR, gBase, csr, cur, degR, inv_r, nN);
    k_pass2S<<<nB, B, 0, stream>>>(bufS, gCntS, inv_s, nN);

    // ---- layer 1: prep, aggregate width 16, 9->64 dense ----
    k_prep<<<gN, B, 0, stream>>>(x, inv_s, xs16, nN);
    k_agg16<<<gQ, B, 0, stream>>>(xs16, z16, csr, cur, degR, nN);
    k_lin1n<<<gN, B, 0, stream>>>(z16, W1, b1, inv_r, inv_s, h1s, warr, nN);

    // ---- layer 2: aggregate width 64, 64->128 dense ----
    k_aggsum64<<<gW, B, 0, stream>>>(h1s, z64, csr, cur, degR, nN);
    k_lin2t<<<(nN + 31) / 32, B, 0, stream>>>(z64, W2, b2, inv_r, inv_s, warr, h2s, nN);

    // ---- layer 3: 128->2, fused aggregation + bias + pooling ----
    k_lin3t<<<gN, B, 0, stream>>>(h2s, W3, t, nN);
    hipMemsetAsync(d_out, 0, (size_t)out_size * 4, stream);
    k_poolf<<<1024, B, 0, stream>>>(t, inv_r, warr, b3, S, R, batch, (float*)d_out, nE, nN, out_size);
}

// Round 5
// 409.031 us; speedup vs baseline: 5.3330x; 1.0672x over previous
//
#include <hip/hip_runtime.h>
#include <hip/hip_bf16.h>
#include <cstddef>

#define BCAP 12288  // per-bucket capacity; mean ~8184, sigma ~90

typedef unsigned short bf16t;
static __device__ __forceinline__ float bf2f(bf16t h) {
    return __uint_as_float(((unsigned)h) << 16);
}
static __device__ __forceinline__ bf16t f2bf(float f) {
    unsigned u = __float_as_uint(f);
    u += 0x7fffu + ((u >> 16) & 1u);  // round-to-nearest-even (finite values)
    return (bf16t)(u >> 16);
}
static __device__ __forceinline__ unsigned pk2(float a, float b) {
    return (unsigned)f2bf(a) | ((unsigned)f2bf(b) << 16);
}

// ---------------- pass 1: bucket edges by receiver AND senders, one read of S/R ----------------
// bufR entry = (r&511)<<23 | s   (needs nN <= 2^23); bufS entry = s&511 (u16)
__global__ void k_bucket(const int* __restrict__ S, const int* __restrict__ R,
                         unsigned* __restrict__ bufR, unsigned short* __restrict__ bufS,
                         int* __restrict__ gCntR, int* __restrict__ gCntS,
                         int nE, int nB) {
    __shared__ int histR[256], baseR[256], histS[256], baseS[256];
    for (int i = threadIdx.x; i < 256; i += blockDim.x) { histR[i] = 0; histS[i] = 0; }
    __syncthreads();
    int chunk = (nE + gridDim.x - 1) / gridDim.x;
    int e0 = blockIdx.x * chunk;
    int e1 = min(e0 + chunk, nE);
    for (int e = e0 + threadIdx.x; e < e1; e += blockDim.x) {
        atomicAdd(&histR[R[e] >> 9], 1);
        atomicAdd(&histS[S[e] >> 9], 1);
    }
    __syncthreads();
    if (threadIdx.x < nB) {
        baseR[threadIdx.x] = atomicAdd(&gCntR[threadIdx.x], histR[threadIdx.x]);
        baseS[threadIdx.x] = atomicAdd(&gCntS[threadIdx.x], histS[threadIdx.x]);
    }
    __syncthreads();
    for (int i = threadIdx.x; i < 256; i += blockDim.x) { histR[i] = 0; histS[i] = 0; }
    __syncthreads();
    for (int e = e0 + threadIdx.x; e < e1; e += blockDim.x) {
        int r = R[e], s = S[e];
        int br = r >> 9;
        int slot = baseR[br] + atomicAdd(&histR[br], 1);
        if (slot < BCAP)
            bufR[(size_t)br * BCAP + slot] = ((unsigned)(r & 511) << 23) | (unsigned)s;
        int bs = s >> 9;
        int slot2 = baseS[bs] + atomicAdd(&histS[bs], 1);
        if (slot2 < BCAP)
            bufS[(size_t)bs * BCAP + slot2] = (unsigned short)(s & 511);
    }
}

// ---------------- pass 2 (fused): per-bucket CSR + degR/inv_r + inv_s + xs prep ----------------
__global__ void k_pass2(const unsigned* __restrict__ bufR, const unsigned short* __restrict__ bufS,
                        const int* __restrict__ gCntR, const int* __restrict__ gCntS,
                        const float* __restrict__ x,
                        int* __restrict__ csr, int* __restrict__ cur, int* __restrict__ degR,
                        float* __restrict__ inv_r, float* __restrict__ inv_s,
                        bf16t* __restrict__ xs, int nN, int nB) {
    __shared__ int hist[512];
    __shared__ int incl[512];
    __shared__ int curs[512];
    __shared__ int sm[256];
    __shared__ int histS[512];
    int t = threadIdx.x;
    int b = blockIdx.x;
    // inline exclusive scan of gCntR -> global edge base for this bucket
    int v = (t < nB) ? gCntR[t] : 0;
    sm[t] = v;
    __syncthreads();
    for (int off = 1; off < 256; off <<= 1) {
        int y = (t >= off) ? sm[t - off] : 0;
        __syncthreads();
        sm[t] += y;
        __syncthreads();
    }
    int gb = (b == 0) ? 0 : sm[b - 1];
    int cnt = gCntR[b];
    __syncthreads();

    const unsigned* buf = bufR + (size_t)b * BCAP;
    for (int i = t; i < 512; i += blockDim.x) { hist[i] = 0; curs[i] = 0; histS[i] = 0; }
    __syncthreads();
    for (int i = t; i < cnt; i += blockDim.x)
        atomicAdd(&hist[buf[i] >> 23], 1);
    __syncthreads();
    // inclusive scan over 512 bins
    int a0 = hist[2 * t], a1 = hist[2 * t + 1];
    int ps = a0 + a1;
    sm[t] = ps;
    __syncthreads();
    for (int off = 1; off < 256; off <<= 1) {
        int y = (t >= off) ? sm[t - off] : 0;
        __syncthreads();
        sm[t] += y;
        __syncthreads();
    }
    int ex = sm[t] - ps;
    incl[2 * t] = ex + a0;
    incl[2 * t + 1] = ex + a0 + a1;
    __syncthreads();
    int n0 = b << 9;
    for (int i = t; i < 512; i += blockDim.x) {
        int n = n0 + i;
        if (n < nN) {
            int d = hist[i];
            degR[n] = d;
            cur[n] = gb + incl[i];  // end offset (agg kernels use cur-deg)
            inv_r[n] = rsqrtf(fmaxf((float)d, 1.f));
        }
    }
    for (int i = t; i < cnt; i += blockDim.x) {
        unsigned p = buf[i];
        int rl = p >> 23;
        int s = p & 0x7FFFFF;
        int pos = gb + (incl[rl] - hist[rl]) + atomicAdd(&curs[rl], 1);
        csr[pos] = s;  // contiguous ~32KB window per block
    }
    // ---- sender part: out-degree -> inv_s, + xs prep (bf16) ----
    int cntS = gCntS[b];
    const unsigned short* bufs = bufS + (size_t)b * BCAP;
    for (int i = t; i < cntS; i += blockDim.x)
        atomicAdd(&histS[bufs[i]], 1);
    __syncthreads();
    for (int i = t; i < 512; i += blockDim.x) {
        int n = n0 + i;
        if (n < nN) {
            float is = rsqrtf(fmaxf((float)histS[i], 1.f));
            inv_s[n] = is;
            float w[9];
#pragma unroll
            for (int k = 0; k < 9; k++) w[k] = x[(size_t)n * 9 + k] * is;
            uint4 pa, pb;
            pa.x = pk2(w[0], w[1]); pa.y = pk2(w[2], w[3]);
            pa.z = pk2(w[4], w[5]); pa.w = pk2(w[6], w[7]);
            pb.x = pk2(w[8], is);   pb.y = 0; pb.z = 0; pb.w = 0;
            uint4* o = (uint4*)(xs + (size_t)n * 16);
            o[0] = pa;
            o[1] = pb;
        }
    }
}

// ---------------- layer-1 aggregation: quarter-wave per node, bf16 width 16 ----------------
__global__ void k_agg16(const bf16t* __restrict__ A, float* __restrict__ Z,
                        const int* __restrict__ csr, const int* __restrict__ cur,
                        const int* __restrict__ degR, int nN) {
    int gid = blockIdx.x * blockDim.x + threadIdx.x;
    int n = gid >> 4;
    int f = threadIdx.x & 15;
    if (n >= nN) return;
    int deg = degR[n];
    int st = cur[n] - deg;
    float s0 = 0.f, s1 = 0.f;
    int i = 0;
    for (; i + 2 <= deg; i += 2) {
        int a = csr[st + i];
        int b = csr[st + i + 1];
        s0 += bf2f(A[(size_t)a * 16 + f]);
        s1 += bf2f(A[(size_t)b * 16 + f]);
    }
    if (i < deg) s0 += bf2f(A[(size_t)csr[st + i] * 16 + f]);
    Z[(size_t)n * 16 + f] = s0 + s1;
}

// ---------------- layer 1 dense: h1s = relu(inv_r*(z16@W1 + w*b1)) * inv_s  (bf16 out) ----------------
__global__ void k_lin1n(const float* __restrict__ Z, const float* __restrict__ W,
                        const float* __restrict__ b, const float* __restrict__ inv_r,
                        const float* __restrict__ inv_s, bf16t* __restrict__ out,
                        float* __restrict__ warr, int nN) {
    __shared__ float Wl[9 * 64];
    __shared__ float bl[64];
    for (int i = threadIdx.x; i < 9 * 64; i += blockDim.x) Wl[i] = W[i];
    if (threadIdx.x < 64) bl[threadIdx.x] = b[threadIdx.x];
    __syncthreads();
    int n = blockIdx.x * blockDim.x + threadIdx.x;
    if (n >= nN) return;
    const float4* zi = (const float4*)(Z + (size_t)n * 16);
    float4 r0 = zi[0], r1 = zi[1], r2 = zi[2];
    float xv[9] = {r0.x, r0.y, r0.z, r0.w, r1.x, r1.y, r1.z, r1.w, r2.x};
    float w = r2.y;
    warr[n] = w;
    float ir = inv_r[n];
    float is = inv_s[n];
    bf16t* o = out + (size_t)n * 64;
#pragma unroll
    for (int c = 0; c < 4; c++) {
        float acc[16];
#pragma unroll
        for (int j = 0; j < 16; j++) acc[j] = w * bl[c * 16 + j];
#pragma unroll
        for (int k = 0; k < 9; k++) {
#pragma unroll
            for (int j = 0; j < 16; j++) acc[j] += xv[k] * Wl[k * 64 + c * 16 + j];
        }
#pragma unroll
        for (int q = 0; q < 4; q++) {
            float v0 = fmaxf(acc[4 * q + 0] * ir, 0.f) * is;
            float v1 = fmaxf(acc[4 * q + 1] * ir, 0.f) * is;
            float v2 = fmaxf(acc[4 * q + 2] * ir, 0.f) * is;
            float v3 = fmaxf(acc[4 * q + 3] * ir, 0.f) * is;
            uint2 pv;
            pv.x = pk2(v0, v1);
            pv.y = pk2(v2, v3);
            *(uint2*)(o + c * 16 + 4 * q) = pv;
        }
    }
}

// ---------------- layer-2 aggregation: wave per node, bf16 row = one 128B line ----------------
__global__ void k_aggsum64(const bf16t* __restrict__ A, float* __restrict__ Z,
                           const int* __restrict__ csr, const int* __restrict__ cur,
                           const int* __restrict__ degR, int nN) {
    int gid = blockIdx.x * blockDim.x + threadIdx.x;
    int n = gid >> 6;
    int lane = threadIdx.x & 63;
    if (n >= nN) return;
    int deg = degR[n];
    int st = cur[n] - deg;
    float s0 = 0.f, s1 = 0.f;
    int i = 0;
    for (; i + 2 <= deg; i += 2) {
        int a = csr[st + i];
        int b = csr[st + i + 1];
        s0 += bf2f(A[(size_t)a * 64 + lane]);
        s1 += bf2f(A[(size_t)b * 64 + lane]);
    }
    if (i < deg) s0 += bf2f(A[(size_t)csr[st + i] * 64 + lane]);
    Z[(size_t)n * 64 + lane] = s0 + s1;
}

// ---------------- layer 2 dense (tiled): h2s = relu(inv_r*(z64@W2 + w*b2)) * inv_s ----------------
__global__ void k_lin2t(const float* __restrict__ Z, const float* __restrict__ W,
                        const float* __restrict__ b, const float* __restrict__ inv_r,
                        const float* __restrict__ inv_s, const float* __restrict__ warr,
                        float* __restrict__ out, int nN) {
    __shared__ float Wl[64 * 128];       // element (k, c*16+q*4+j) at k*128 + q*32 + c*4 + j
    __shared__ float Xl[32 * 68];
    __shared__ float bl[128];
    for (int m = threadIdx.x; m < 2048; m += blockDim.x) {
        float4 wv = ((const float4*)W)[m];
        int k = m >> 5, rem = m & 31, c = rem >> 2, q = rem & 3;
        *(float4*)(Wl + k * 128 + q * 32 + c * 4) = wv;
    }
    for (int i = threadIdx.x; i < 128; i += blockDim.x) bl[i] = b[i];
    int nb = blockIdx.x * 32;
    for (int idx = threadIdx.x; idx < 32 * 16; idx += blockDim.x) {
        int node = idx >> 4, k4 = idx & 15;
        float4 v = make_float4(0.f, 0.f, 0.f, 0.f);
        if (nb + node < nN) v = ((const float4*)(Z + (size_t)(nb + node) * 64))[k4];
        Xl[node * 68 + k4 * 4 + 0] = v.x;
        Xl[node * 68 + k4 * 4 + 1] = v.y;
        Xl[node * 68 + k4 * 4 + 2] = v.z;
        Xl[node * 68 + k4 * 4 + 3] = v.w;
    }
    __syncthreads();
    int nl = threadIdx.x >> 3;
    int c = threadIdx.x & 7;
    int n = nb + nl;
    if (n >= nN) return;
    float w = warr[n];
    float acc[16];
#pragma unroll
    for (int q = 0; q < 4; q++)
#pragma unroll
        for (int j = 0; j < 4; j++) acc[q * 4 + j] = w * bl[c * 16 + q * 4 + j];
#pragma unroll 8
    for (int k = 0; k < 64; k++) {
        float xv = Xl[nl * 68 + k];
        const float* wr = Wl + k * 128 + c * 4;
#pragma unroll
        for (int q = 0; q < 4; q++) {
            float4 wv = *(const float4*)(wr + q * 32);
            acc[q * 4 + 0] += xv * wv.x;
            acc[q * 4 + 1] += xv * wv.y;
            acc[q * 4 + 2] += xv * wv.z;
            acc[q * 4 + 3] += xv * wv.w;
        }
    }
    float ir = inv_r[n];
    float is = inv_s[n];
    float* o = out + (size_t)n * 128 + c * 16;
#pragma unroll
    for (int q = 0; q < 4; q++) {
        float4 v = make_float4(fmaxf(acc[q * 4 + 0] * ir, 0.f) * is,
                               fmaxf(acc[q * 4 + 1] * ir, 0.f) * is,
                               fmaxf(acc[q * 4 + 2] * ir, 0.f) * is,
                               fmaxf(acc[q * 4 + 3] * ir, 0.f) * is);
        *(float4*)(o + q * 4) = v;
    }
}

// ---------------- layer 3 dense: t = h2s @ W3 ----------------
__global__ void k_lin3t(const float* __restrict__ in, const float* __restrict__ W,
                        float* __restrict__ out, int nN) {
    __shared__ float Wl[128 * 2];
    for (int i = threadIdx.x; i < 256; i += blockDim.x) Wl[i] = W[i];
    __syncthreads();
    int n = blockIdx.x * blockDim.x + threadIdx.x;
    if (n >= nN) return;
    float acc0 = 0.f, acc1 = 0.f;
    const float4* xin = (const float4*)(in + (size_t)n * 128);
#pragma unroll 8
    for (int k4 = 0; k4 < 32; k4++) {
        float4 v = xin[k4];
        int k = 4 * k4;
        acc0 += v.x * Wl[(k + 0) * 2] + v.y * Wl[(k + 1) * 2] + v.z * Wl[(k + 2) * 2] + v.w * Wl[(k + 3) * 2];
        acc1 += v.x * Wl[(k + 0) * 2 + 1] + v.y * Wl[(k + 1) * 2 + 1] + v.z * Wl[(k + 2) * 2 + 1] + v.w * Wl[(k + 3) * 2 + 1];
    }
    *(float2*)(out + (size_t)n * 2) = make_float2(acc0, acc1);
}

// ---------------- fused layer-3 aggregation + bias + pooling ----------------
__global__ void k_poolf(const float* __restrict__ t, const float* __restrict__ inv_r,
                        const float* __restrict__ warr, const float* __restrict__ b3,
                        const int* __restrict__ S, const int* __restrict__ R,
                        const int* __restrict__ batch, float* out,
                        int nE, int nN, int outSize) {
    __shared__ float sm[256];
    for (int i = threadIdx.x; i < 256; i += blockDim.x) sm[i] = 0.f;
    __syncthreads();
    float b30 = b3[0], b31 = b3[1];
    for (int e = blockIdx.x * blockDim.x + threadIdx.x; e < nE; e += gridDim.x * blockDim.x) {
        int r = R[e];
        int s = S[e];
        float ir = inv_r[r];
        int g = batch[r];
        float2 v = ((const float2*)t)[s];
        atomicAdd(&sm[2 * g + 0], v.x * ir);
        atomicAdd(&sm[2 * g + 1], v.y * ir);
    }
    for (int n = blockIdx.x * blockDim.x + threadIdx.x; n < nN; n += gridDim.x * blockDim.x) {
        float c = inv_r[n] * warr[n];
        int g = batch[n];
        atomicAdd(&sm[2 * g + 0], c * b30);
        atomicAdd(&sm[2 * g + 1], c * b31);
    }
    __syncthreads();
    for (int i = threadIdx.x; i < outSize; i += blockDim.x) atomicAdd(&out[i], sm[i]);
}

extern "C" void kernel_launch(void* const* d_in, const int* in_sizes, int n_in,
                              void* d_out, int out_size, void* d_ws, size_t ws_size,
                              hipStream_t stream) {
    const float* x     = (const float*)d_in[0];
    const int*   S     = (const int*)d_in[1];
    const int*   R     = (const int*)d_in[2];
    const int*   batch = (const int*)d_in[3];
    const float* W1 = (const float*)d_in[5];
    const float* b1 = (const float*)d_in[6];
    const float* W2 = (const float*)d_in[7];
    const float* b2 = (const float*)d_in[8];
    const float* W3 = (const float*)d_in[9];
    const float* b3 = (const float*)d_in[10];

    int nN = in_sizes[0] / 9;
    int nE = in_sizes[1];
    int nB = (nN + 511) / 512;  // buckets of 512 nodes; requires nB <= 256

    char* ws = (char*)d_ws;
    int*   cur   = (int*)ws;                         // nN
    int*   degR  = cur + nN;                         // nN
    float* inv_s = (float*)(degR + nN);              // nN
    float* inv_r = inv_s + nN;                       // nN
    float* warr  = inv_r + nN;                       // nN
    int*   gCntR = (int*)(warr + nN);                // 256
    int*   gCntS = gCntR + 256;                      // 256
    int*   csr   = gCntS + 256;                      // nE
    bf16t* xs    = (bf16t*)(csr + nE);               // nN*16 bf16 (3.2 MB, L2-resident)
    float* regA  = (float*)(xs + (size_t)nN * 16);   // 51.2 MB region
    // aliasing within regA (lifetimes disjoint):
    unsigned*       bufR = (unsigned*)regA;                       // 256*BCAP u32 = 12.6 MB
    unsigned short* bufS = (unsigned short*)(bufR + 256 * BCAP);  // 6.3 MB
    float* z16   = regA;                             // nN*16 fp32 (after build)
    bf16t* h1s   = (bf16t*)(regA + (size_t)nN * 16); // nN*64 bf16 (12.8 MB)
    float* h2s   = regA;                             // nN*128 fp32 (z16+h1s dead by then)
    float* regB  = regA + (size_t)nN * 128;          // 25.6 MB region
    float* z64   = regB;                             // nN*64 fp32
    float* t     = regB;                             // nN*2 (z64 dead after lin2t)

    const int B = 256;
    int gN = (nN + B - 1) / B;
    int gQ = (int)(((size_t)nN * 16 + B - 1) / B);
    int gW = (int)(((size_t)nN * 64 + B - 1) / B);

    // ---- CSR + degrees + inv_s + xs via fused bucket sort ----
    hipMemsetAsync(gCntR, 0, 512 * 4, stream);
    k_bucket<<<256, B, 0, stream>>>(S, R, bufR, bufS, gCntR, gCntS, nE, nB);
    k_pass2<<<nB, B, 0, stream>>>(bufR, bufS, gCntR, gCntS, x, csr, cur, degR,
                                  inv_r, inv_s, xs, nN, nB);

    // ---- layer 1: aggregate width 16 (bf16, L2-resident), 9->64 dense ----
    k_agg16<<<gQ, B, 0, stream>>>(xs, z16, csr, cur, degR, nN);
    k_lin1n<<<gN, B, 0, stream>>>(z16, W1, b1, inv_r, inv_s, h1s, warr, nN);

    // ---- layer 2: aggregate width 64 (bf16 row = one 128B line), 64->128 dense ----
    k_aggsum64<<<gW, B, 0, stream>>>(h1s, z64, csr, cur, degR, nN);
    k_lin2t<<<(nN + 31) / 32, B, 0, stream>>>(z64, W2, b2, inv_r, inv_s, warr, h2s, nN);

    // ---- layer 3: 128->2, fused aggregation + bias + pooling ----
    k_lin3t<<<gN, B, 0, stream>>>(h2s, W3, t, nN);
    hipMemsetAsync(d_out, 0, (size_t)out_size * 4, stream);
    k_poolf<<<1024, B, 0, stream>>>(t, inv_r, warr, b3, S, R, batch, (float*)d_out, nE, nN, out_size);
}

// Round 6
// 331.557 us; speedup vs baseline: 6.5791x; 1.2337x over previous
//
#include <hip/hip_runtime.h>
#include <hip/hip_bf16.h>
#include <cstddef>

#define BCAP 12288  // per-bucket capacity; mean ~8184, sigma ~90

typedef unsigned short bf16t;
static __device__ __forceinline__ float bf2f(bf16t h) {
    return __uint_as_float(((unsigned)h) << 16);
}
static __device__ __forceinline__ bf16t f2bf(float f) {
    unsigned u = __float_as_uint(f);
    u += 0x7fffu + ((u >> 16) & 1u);  // round-to-nearest-even (finite values)
    return (bf16t)(u >> 16);
}
static __device__ __forceinline__ unsigned pk2(float a, float b) {
    return (unsigned)f2bf(a) | ((unsigned)f2bf(b) << 16);
}

// ---------------- pass 1: bucket edges by receiver AND senders, one read of S/R ----------------
// bufR entry = (r&511)<<23 | s   (needs nN <= 2^23); bufS entry = s&511 (u16)
__global__ void k_bucket(const int* __restrict__ S, const int* __restrict__ R,
                         unsigned* __restrict__ bufR, unsigned short* __restrict__ bufS,
                         int* __restrict__ gCntR, int* __restrict__ gCntS,
                         int nE, int nB) {
    __shared__ int histR[256], baseR[256], histS[256], baseS[256];
    for (int i = threadIdx.x; i < 256; i += blockDim.x) { histR[i] = 0; histS[i] = 0; }
    __syncthreads();
    int chunk = (nE + gridDim.x - 1) / gridDim.x;
    int e0 = blockIdx.x * chunk;
    int e1 = min(e0 + chunk, nE);
    for (int e = e0 + threadIdx.x; e < e1; e += blockDim.x) {
        atomicAdd(&histR[R[e] >> 9], 1);
        atomicAdd(&histS[S[e] >> 9], 1);
    }
    __syncthreads();
    if (threadIdx.x < nB) {
        baseR[threadIdx.x] = atomicAdd(&gCntR[threadIdx.x], histR[threadIdx.x]);
        baseS[threadIdx.x] = atomicAdd(&gCntS[threadIdx.x], histS[threadIdx.x]);
    }
    __syncthreads();
    for (int i = threadIdx.x; i < 256; i += blockDim.x) { histR[i] = 0; histS[i] = 0; }
    __syncthreads();
    for (int e = e0 + threadIdx.x; e < e1; e += blockDim.x) {
        int r = R[e], s = S[e];
        int br = r >> 9;
        int slot = baseR[br] + atomicAdd(&histR[br], 1);
        if (slot < BCAP)
            bufR[(size_t)br * BCAP + slot] = ((unsigned)(r & 511) << 23) | (unsigned)s;
        int bs = s >> 9;
        int slot2 = baseS[bs] + atomicAdd(&histS[bs], 1);
        if (slot2 < BCAP)
            bufS[(size_t)bs * BCAP + slot2] = (unsigned short)(s & 511);
    }
}

// ---------------- pass 2 (fused): per-bucket CSR + degR/inv_r + inv_s + xs prep ----------------
__global__ void k_pass2(const unsigned* __restrict__ bufR, const unsigned short* __restrict__ bufS,
                        const int* __restrict__ gCntR, const int* __restrict__ gCntS,
                        const float* __restrict__ x,
                        int* __restrict__ csr, int* __restrict__ cur, int* __restrict__ degR,
                        float* __restrict__ inv_r, float* __restrict__ inv_s,
                        bf16t* __restrict__ xs, int nN, int nB) {
    __shared__ int hist[512];
    __shared__ int incl[512];
    __shared__ int curs[512];
    __shared__ int sm[256];
    __shared__ int histS[512];
    int t = threadIdx.x;
    int b = blockIdx.x;
    // inline exclusive scan of gCntR -> global edge base for this bucket
    int v = (t < nB) ? gCntR[t] : 0;
    sm[t] = v;
    __syncthreads();
    for (int off = 1; off < 256; off <<= 1) {
        int y = (t >= off) ? sm[t - off] : 0;
        __syncthreads();
        sm[t] += y;
        __syncthreads();
    }
    int gb = (b == 0) ? 0 : sm[b - 1];
    int cnt = gCntR[b];
    __syncthreads();

    const unsigned* buf = bufR + (size_t)b * BCAP;
    for (int i = t; i < 512; i += blockDim.x) { hist[i] = 0; curs[i] = 0; histS[i] = 0; }
    __syncthreads();
    for (int i = t; i < cnt; i += blockDim.x)
        atomicAdd(&hist[buf[i] >> 23], 1);
    __syncthreads();
    // inclusive scan over 512 bins
    int a0 = hist[2 * t], a1 = hist[2 * t + 1];
    int ps = a0 + a1;
    sm[t] = ps;
    __syncthreads();
    for (int off = 1; off < 256; off <<= 1) {
        int y = (t >= off) ? sm[t - off] : 0;
        __syncthreads();
        sm[t] += y;
        __syncthreads();
    }
    int ex = sm[t] - ps;
    incl[2 * t] = ex + a0;
    incl[2 * t + 1] = ex + a0 + a1;
    __syncthreads();
    int n0 = b << 9;
    for (int i = t; i < 512; i += blockDim.x) {
        int n = n0 + i;
        if (n < nN) {
            int d = hist[i];
            degR[n] = d;
            cur[n] = gb + incl[i];  // end offset (agg kernels use cur-deg)
            inv_r[n] = rsqrtf(fmaxf((float)d, 1.f));
        }
    }
    for (int i = t; i < cnt; i += blockDim.x) {
        unsigned p = buf[i];
        int rl = p >> 23;
        int s = p & 0x7FFFFF;
        int pos = gb + (incl[rl] - hist[rl]) + atomicAdd(&curs[rl], 1);
        csr[pos] = s;  // contiguous ~32KB window per block
    }
    // ---- sender part: out-degree -> inv_s, + xs prep (bf16) ----
    int cntS = gCntS[b];
    const unsigned short* bufs = bufS + (size_t)b * BCAP;
    for (int i = t; i < cntS; i += blockDim.x)
        atomicAdd(&histS[bufs[i]], 1);
    __syncthreads();
    for (int i = t; i < 512; i += blockDim.x) {
        int n = n0 + i;
        if (n < nN) {
            float is = rsqrtf(fmaxf((float)histS[i], 1.f));
            inv_s[n] = is;
            float w[9];
#pragma unroll
            for (int k = 0; k < 9; k++) w[k] = x[(size_t)n * 9 + k] * is;
            uint4 pa, pb;
            pa.x = pk2(w[0], w[1]); pa.y = pk2(w[2], w[3]);
            pa.z = pk2(w[4], w[5]); pa.w = pk2(w[6], w[7]);
            pb.x = pk2(w[8], is);   pb.y = 0; pb.z = 0; pb.w = 0;
            uint4* o = (uint4*)(xs + (size_t)n * 16);
            o[0] = pa;
            o[1] = pb;
        }
    }
}

// ---------------- layer-1 aggregation: quarter-wave per node, bf16 width 16, unroll-4 ----------------
__global__ void k_agg16(const bf16t* __restrict__ A, float* __restrict__ Z,
                        const int* __restrict__ csr, const int* __restrict__ cur,
                        const int* __restrict__ degR, int nN) {
    int gid = blockIdx.x * blockDim.x + threadIdx.x;
    int n = gid >> 4;
    int f = threadIdx.x & 15;
    if (n >= nN) return;
    int deg = degR[n];
    int st = cur[n] - deg;
    float s0 = 0.f, s1 = 0.f, s2 = 0.f, s3 = 0.f;
    int i = 0;
    for (; i + 4 <= deg; i += 4) {
        int a = csr[st + i], b = csr[st + i + 1], c = csr[st + i + 2], d = csr[st + i + 3];
        s0 += bf2f(A[(size_t)a * 16 + f]);
        s1 += bf2f(A[(size_t)b * 16 + f]);
        s2 += bf2f(A[(size_t)c * 16 + f]);
        s3 += bf2f(A[(size_t)d * 16 + f]);
    }
    for (; i < deg; i++) s0 += bf2f(A[(size_t)csr[st + i] * 16 + f]);
    Z[(size_t)n * 16 + f] = (s0 + s1) + (s2 + s3);
}

// ---------------- layer 1 dense: h1s = relu(inv_r*(z16@W1 + w*b1)) * inv_s  (bf16 out) ----------------
__global__ void k_lin1n(const float* __restrict__ Z, const float* __restrict__ W,
                        const float* __restrict__ b, const float* __restrict__ inv_r,
                        const float* __restrict__ inv_s, bf16t* __restrict__ out,
                        float* __restrict__ warr, int nN) {
    __shared__ float Wl[9 * 64];
    __shared__ float bl[64];
    for (int i = threadIdx.x; i < 9 * 64; i += blockDim.x) Wl[i] = W[i];
    if (threadIdx.x < 64) bl[threadIdx.x] = b[threadIdx.x];
    __syncthreads();
    int n = blockIdx.x * blockDim.x + threadIdx.x;
    if (n >= nN) return;
    const float4* zi = (const float4*)(Z + (size_t)n * 16);
    float4 r0 = zi[0], r1 = zi[1], r2 = zi[2];
    float xv[9] = {r0.x, r0.y, r0.z, r0.w, r1.x, r1.y, r1.z, r1.w, r2.x};
    float w = r2.y;
    warr[n] = w;
    float ir = inv_r[n];
    float is = inv_s[n];
    bf16t* o = out + (size_t)n * 64;
#pragma unroll
    for (int c = 0; c < 4; c++) {
        float acc[16];
#pragma unroll
        for (int j = 0; j < 16; j++) acc[j] = w * bl[c * 16 + j];
#pragma unroll
        for (int k = 0; k < 9; k++) {
#pragma unroll
            for (int j = 0; j < 16; j++) acc[j] += xv[k] * Wl[k * 64 + c * 16 + j];
        }
#pragma unroll
        for (int q = 0; q < 4; q++) {
            float v0 = fmaxf(acc[4 * q + 0] * ir, 0.f) * is;
            float v1 = fmaxf(acc[4 * q + 1] * ir, 0.f) * is;
            float v2 = fmaxf(acc[4 * q + 2] * ir, 0.f) * is;
            float v3 = fmaxf(acc[4 * q + 3] * ir, 0.f) * is;
            uint2 pv;
            pv.x = pk2(v0, v1);
            pv.y = pk2(v2, v3);
            *(uint2*)(o + c * 16 + 4 * q) = pv;
        }
    }
}

// ---------------- layer-2 aggregation: wave per node, bf16 row = one 128B line, unroll-4 ----------------
__global__ void k_aggsum64(const bf16t* __restrict__ A, float* __restrict__ Z,
                           const int* __restrict__ csr, const int* __restrict__ cur,
                           const int* __restrict__ degR, int nN) {
    int gid = blockIdx.x * blockDim.x + threadIdx.x;
    int n = gid >> 6;
    int lane = threadIdx.x & 63;
    if (n >= nN) return;
    int deg = degR[n];
    int st = cur[n] - deg;
    float s0 = 0.f, s1 = 0.f, s2 = 0.f, s3 = 0.f;
    int i = 0;
    for (; i + 4 <= deg; i += 4) {
        int a = csr[st + i], b = csr[st + i + 1], c = csr[st + i + 2], d = csr[st + i + 3];
        s0 += bf2f(A[(size_t)a * 64 + lane]);
        s1 += bf2f(A[(size_t)b * 64 + lane]);
        s2 += bf2f(A[(size_t)c * 64 + lane]);
        s3 += bf2f(A[(size_t)d * 64 + lane]);
    }
    for (; i < deg; i++) s0 += bf2f(A[(size_t)csr[st + i] * 64 + lane]);
    Z[(size_t)n * 64 + lane] = (s0 + s1) + (s2 + s3);
}

// ---------------- fused layers 2+3 dense: t = (relu(inv_r*(z64@W2 + w*b2))*inv_s) @ W3 ----------------
// block = 32 nodes x 8 col-tiles; h2 never hits memory
__global__ void k_lin23(const float* __restrict__ Z, const float* __restrict__ W,
                        const float* __restrict__ b, const float* __restrict__ W3,
                        const float* __restrict__ inv_r, const float* __restrict__ inv_s,
                        const float* __restrict__ warr, float* __restrict__ t, int nN) {
    __shared__ float Wl[64 * 128];       // element (k, c*16+q*4+j) at k*128 + q*32 + c*4 + j
    __shared__ float Xl[32 * 68];
    __shared__ float bl[128];
    __shared__ float W3l[256];
    for (int m = threadIdx.x; m < 2048; m += blockDim.x) {
        float4 wv = ((const float4*)W)[m];
        int k = m >> 5, rem = m & 31, c = rem >> 2, q = rem & 3;
        *(float4*)(Wl + k * 128 + q * 32 + c * 4) = wv;
    }
    for (int i = threadIdx.x; i < 128; i += blockDim.x) bl[i] = b[i];
    for (int i = threadIdx.x; i < 256; i += blockDim.x) W3l[i] = W3[i];
    int nb = blockIdx.x * 32;
    for (int idx = threadIdx.x; idx < 32 * 16; idx += blockDim.x) {
        int node = idx >> 4, k4 = idx & 15;
        float4 v = make_float4(0.f, 0.f, 0.f, 0.f);
        if (nb + node < nN) v = ((const float4*)(Z + (size_t)(nb + node) * 64))[k4];
        Xl[node * 68 + k4 * 4 + 0] = v.x;
        Xl[node * 68 + k4 * 4 + 1] = v.y;
        Xl[node * 68 + k4 * 4 + 2] = v.z;
        Xl[node * 68 + k4 * 4 + 3] = v.w;
    }
    __syncthreads();
    int nl = threadIdx.x >> 3;
    int c = threadIdx.x & 7;
    int n = nb + nl;
    if (n >= nN) return;  // whole 8-lane group exits together (shuffles below stay in-group)
    float w = warr[n];
    float acc[16];
#pragma unroll
    for (int q = 0; q < 4; q++)
#pragma unroll
        for (int j = 0; j < 4; j++) acc[q * 4 + j] = w * bl[c * 16 + q * 4 + j];
#pragma unroll 8
    for (int k = 0; k < 64; k++) {
        float xv = Xl[nl * 68 + k];
        const float* wr = Wl + k * 128 + c * 4;
#pragma unroll
        for (int q = 0; q < 4; q++) {
            float4 wv = *(const float4*)(wr + q * 32);
            acc[q * 4 + 0] += xv * wv.x;
            acc[q * 4 + 1] += xv * wv.y;
            acc[q * 4 + 2] += xv * wv.z;
            acc[q * 4 + 3] += xv * wv.w;
        }
    }
    float ir = inv_r[n];
    float is = inv_s[n];
    float p0 = 0.f, p1 = 0.f;
#pragma unroll
    for (int q = 0; q < 4; q++) {
#pragma unroll
        for (int j = 0; j < 4; j++) {
            float h = fmaxf(acc[q * 4 + j] * ir, 0.f) * is;
            int col = c * 16 + q * 4 + j;
            p0 += h * W3l[col * 2 + 0];
            p1 += h * W3l[col * 2 + 1];
        }
    }
    // reduce across the 8 c-lanes of this node (lanes nl*8..nl*8+7 within the wave)
    p0 += __shfl_xor(p0, 1); p1 += __shfl_xor(p1, 1);
    p0 += __shfl_xor(p0, 2); p1 += __shfl_xor(p1, 2);
    p0 += __shfl_xor(p0, 4); p1 += __shfl_xor(p1, 4);
    if (c == 0) *(float2*)(t + (size_t)n * 2) = make_float2(p0, p1);
}

// ---------------- pooling (node-parallel over CSR): out[batch[n]] += inv_r[n]*(sum t[s] + w[n]*b3) ----------------
__global__ void k_poolg(const float* __restrict__ t, const float* __restrict__ inv_r,
                        const float* __restrict__ warr, const float* __restrict__ b3,
                        const int* __restrict__ csr, const int* __restrict__ cur,
                        const int* __restrict__ degR, const int* __restrict__ batch,
                        float* out, int nN, int outSize) {
    __shared__ float sm[256];
    for (int i = threadIdx.x; i < 256; i += blockDim.x) sm[i] = 0.f;
    __syncthreads();
    int n = blockIdx.x * blockDim.x + threadIdx.x;
    if (n < nN) {
        int deg = degR[n];
        int st = cur[n] - deg;
        float a0 = 0.f, a1 = 0.f, c0 = 0.f, c1 = 0.f;
        int i = 0;
        for (; i + 2 <= deg; i += 2) {
            int sa = csr[st + i], sb = csr[st + i + 1];
            float2 va = ((const float2*)t)[sa];
            float2 vb = ((const float2*)t)[sb];
            a0 += va.x; a1 += va.y;
            c0 += vb.x; c1 += vb.y;
        }
        if (i < deg) {
            float2 va = ((const float2*)t)[csr[st + i]];
            a0 += va.x; a1 += va.y;
        }
        float ir = inv_r[n];
        float wb = warr[n] * ir;
        int g = batch[n];
        atomicAdd(&sm[2 * g + 0], (a0 + c0) * ir + wb * b3[0]);
        atomicAdd(&sm[2 * g + 1], (a1 + c1) * ir + wb * b3[1]);
    }
    __syncthreads();
    for (int i = threadIdx.x; i < outSize; i += blockDim.x) atomicAdd(&out[i], sm[i]);
}

extern "C" void kernel_launch(void* const* d_in, const int* in_sizes, int n_in,
                              void* d_out, int out_size, void* d_ws, size_t ws_size,
                              hipStream_t stream) {
    const float* x     = (const float*)d_in[0];
    const int*   S     = (const int*)d_in[1];
    const int*   R     = (const int*)d_in[2];
    const int*   batch = (const int*)d_in[3];
    const float* W1 = (const float*)d_in[5];
    const float* b1 = (const float*)d_in[6];
    const float* W2 = (const float*)d_in[7];
    const float* b2 = (const float*)d_in[8];
    const float* W3 = (const float*)d_in[9];
    const float* b3 = (const float*)d_in[10];

    int nN = in_sizes[0] / 9;
    int nE = in_sizes[1];
    int nB = (nN + 511) / 512;  // buckets of 512 nodes; requires nB <= 256

    char* ws = (char*)d_ws;
    int*   cur   = (int*)ws;                         // nN
    int*   degR  = cur + nN;                         // nN
    float* inv_s = (float*)(degR + nN);              // nN
    float* inv_r = inv_s + nN;                       // nN
    float* warr  = inv_r + nN;                       // nN
    int*   gCntR = (int*)(warr + nN);                // 256
    int*   gCntS = gCntR + 256;                      // 256
    int*   csr   = gCntS + 256;                      // nE
    bf16t* xs    = (bf16t*)(csr + nE);               // nN*16 bf16 (3.2 MB)
    float* regA  = (float*)(xs + (size_t)nN * 16);   // big region
    // aliasing within regA (lifetimes disjoint):
    unsigned*       bufR = (unsigned*)regA;                       // 256*BCAP u32 = 12.6 MB
    unsigned short* bufS = (unsigned short*)(bufR + 256 * BCAP);  // 6.3 MB
    float* z16   = regA;                             // nN*16 fp32 (after build)
    bf16t* h1s   = (bf16t*)(regA + (size_t)nN * 16); // nN*64 bf16 (12.8 MB)
    float* regB  = regA + (size_t)nN * 48;           // after z16+h1s
    float* z64   = regB;                             // nN*64 fp32 (25.6 MB)
    float* t     = regB + (size_t)nN * 64;           // nN*2 fp32

    const int B = 256;
    int gN = (nN + B - 1) / B;
    int gQ = (int)(((size_t)nN * 16 + B - 1) / B);
    int gW = (int)(((size_t)nN * 64 + B - 1) / B);

    // ---- CSR + degrees + inv_s + xs via fused bucket sort ----
    hipMemsetAsync(gCntR, 0, 512 * 4, stream);
    k_bucket<<<256, B, 0, stream>>>(S, R, bufR, bufS, gCntR, gCntS, nE, nB);
    k_pass2<<<nB, B, 0, stream>>>(bufR, bufS, gCntR, gCntS, x, csr, cur, degR,
                                  inv_r, inv_s, xs, nN, nB);

    // ---- layer 1: aggregate width 16 (bf16), 9->64 dense ----
    k_agg16<<<gQ, B, 0, stream>>>(xs, z16, csr, cur, degR, nN);
    k_lin1n<<<gN, B, 0, stream>>>(z16, W1, b1, inv_r, inv_s, h1s, warr, nN);

    // ---- layer 2: aggregate width 64 (bf16 row = one 128B line), fused 64->128->2 dense ----
    k_aggsum64<<<gW, B, 0, stream>>>(h1s, z64, csr, cur, degR, nN);
    k_lin23<<<(nN + 31) / 32, B, 0, stream>>>(z64, W2, b2, W3, inv_r, inv_s, warr, t, nN);

    // ---- fused layer-3 aggregation + bias + pooling (node-parallel over CSR) ----
    hipMemsetAsync(d_out, 0, (size_t)out_size * 4, stream);
    k_poolg<<<gN, B, 0, stream>>>(t, inv_r, warr, b3, csr, cur, degR, batch,
                                  (float*)d_out, nN, out_size);
}

// Round 7
// 257.973 us; speedup vs baseline: 8.4558x; 1.2852x over previous
//
#include <hip/hip_runtime.h>
#include <hip/hip_bf16.h>
#include <cstddef>

#define BCAP 12288  // per-bucket capacity; mean ~8184, sigma ~90

typedef unsigned short bf16t;
typedef __attribute__((ext_vector_type(8))) short short8;
typedef __attribute__((ext_vector_type(4))) float f32x4;

static __device__ __forceinline__ float bf2f(unsigned h16) {
    return __uint_as_float(h16 << 16);
}
static __device__ __forceinline__ bf16t f2bf(float f) {
    unsigned u = __float_as_uint(f);
    u += 0x7fffu + ((u >> 16) & 1u);  // round-to-nearest-even (finite values)
    return (bf16t)(u >> 16);
}
static __device__ __forceinline__ unsigned pk2(float a, float b) {
    return (unsigned)f2bf(a) | ((unsigned)f2bf(b) << 16);
}

// ---------------- pass 1: bucket edges by receiver AND senders, one read of S/R ----------------
__global__ void k_bucket(const int* __restrict__ S, const int* __restrict__ R,
                         unsigned* __restrict__ bufR, unsigned short* __restrict__ bufS,
                         int* __restrict__ gCntR, int* __restrict__ gCntS,
                         int nE, int nB) {
    __shared__ int histR[256], baseR[256], histS[256], baseS[256];
    for (int i = threadIdx.x; i < 256; i += blockDim.x) { histR[i] = 0; histS[i] = 0; }
    __syncthreads();
    int chunk = (nE + gridDim.x - 1) / gridDim.x;
    int e0 = blockIdx.x * chunk;
    int e1 = min(e0 + chunk, nE);
    for (int e = e0 + threadIdx.x; e < e1; e += blockDim.x) {
        atomicAdd(&histR[R[e] >> 9], 1);
        atomicAdd(&histS[S[e] >> 9], 1);
    }
    __syncthreads();
    if (threadIdx.x < nB) {
        baseR[threadIdx.x] = atomicAdd(&gCntR[threadIdx.x], histR[threadIdx.x]);
        baseS[threadIdx.x] = atomicAdd(&gCntS[threadIdx.x], histS[threadIdx.x]);
    }
    __syncthreads();
    for (int i = threadIdx.x; i < 256; i += blockDim.x) { histR[i] = 0; histS[i] = 0; }
    __syncthreads();
    for (int e = e0 + threadIdx.x; e < e1; e += blockDim.x) {
        int r = R[e], s = S[e];
        int br = r >> 9;
        int slot = baseR[br] + atomicAdd(&histR[br], 1);
        if (slot < BCAP)
            bufR[(size_t)br * BCAP + slot] = ((unsigned)(r & 511) << 23) | (unsigned)s;
        int bs = s >> 9;
        int slot2 = baseS[bs] + atomicAdd(&histS[bs], 1);
        if (slot2 < BCAP)
            bufS[(size_t)bs * BCAP + slot2] = (unsigned short)(s & 511);
    }
}

// ---------------- pass 2 (fused): per-bucket CSR + degR/inv_r + inv_s + xs prep ----------------
__global__ void k_pass2(const unsigned* __restrict__ bufR, const unsigned short* __restrict__ bufS,
                        const int* __restrict__ gCntR, const int* __restrict__ gCntS,
                        const float* __restrict__ x,
                        int* __restrict__ csr, int* __restrict__ cur, int* __restrict__ degR,
                        float* __restrict__ inv_r, float* __restrict__ inv_s,
                        bf16t* __restrict__ xs, int nN, int nB) {
    __shared__ int hist[512];
    __shared__ int incl[512];
    __shared__ int curs[512];
    __shared__ int sm[256];
    __shared__ int histS[512];
    int t = threadIdx.x;
    int b = blockIdx.x;
    int v = (t < nB) ? gCntR[t] : 0;
    sm[t] = v;
    __syncthreads();
    for (int off = 1; off < 256; off <<= 1) {
        int y = (t >= off) ? sm[t - off] : 0;
        __syncthreads();
        sm[t] += y;
        __syncthreads();
    }
    int gb = (b == 0) ? 0 : sm[b - 1];
    int cnt = gCntR[b];
    __syncthreads();

    const unsigned* buf = bufR + (size_t)b * BCAP;
    for (int i = t; i < 512; i += blockDim.x) { hist[i] = 0; curs[i] = 0; histS[i] = 0; }
    __syncthreads();
    for (int i = t; i < cnt; i += blockDim.x)
        atomicAdd(&hist[buf[i] >> 23], 1);
    __syncthreads();
    int a0 = hist[2 * t], a1 = hist[2 * t + 1];
    int ps = a0 + a1;
    sm[t] = ps;
    __syncthreads();
    for (int off = 1; off < 256; off <<= 1) {
        int y = (t >= off) ? sm[t - off] : 0;
        __syncthreads();
        sm[t] += y;
        __syncthreads();
    }
    int ex = sm[t] - ps;
    incl[2 * t] = ex + a0;
    incl[2 * t + 1] = ex + a0 + a1;
    __syncthreads();
    int n0 = b << 9;
    for (int i = t; i < 512; i += blockDim.x) {
        int n = n0 + i;
        if (n < nN) {
            int d = hist[i];
            degR[n] = d;
            cur[n] = gb + incl[i];  // end offset (agg kernels use cur-deg)
            inv_r[n] = rsqrtf(fmaxf((float)d, 1.f));
        }
    }
    for (int i = t; i < cnt; i += blockDim.x) {
        unsigned p = buf[i];
        int rl = p >> 23;
        int s = p & 0x7FFFFF;
        int pos = gb + (incl[rl] - hist[rl]) + atomicAdd(&curs[rl], 1);
        csr[pos] = s;
    }
    // ---- sender part: out-degree -> inv_s, + xs prep (bf16) ----
    int cntS = gCntS[b];
    const unsigned short* bufs = bufS + (size_t)b * BCAP;
    for (int i = t; i < cntS; i += blockDim.x)
        atomicAdd(&histS[bufs[i]], 1);
    __syncthreads();
    for (int i = t; i < 512; i += blockDim.x) {
        int n = n0 + i;
        if (n < nN) {
            float is = rsqrtf(fmaxf((float)histS[i], 1.f));
            inv_s[n] = is;
            float w[9];
#pragma unroll
            for (int k = 0; k < 9; k++) w[k] = x[(size_t)n * 9 + k] * is;
            uint4 pa, pb;
            pa.x = pk2(w[0], w[1]); pa.y = pk2(w[2], w[3]);
            pa.z = pk2(w[4], w[5]); pa.w = pk2(w[6], w[7]);
            pb.x = pk2(w[8], is);   pb.y = 0; pb.z = 0; pb.w = 0;
            uint4* o = (uint4*)(xs + (size_t)n * 16);
            o[0] = pa;
            o[1] = pb;
        }
    }
}

// ---------------- W2 -> B-fragment prep (bf16, MFMA B^T frag layout) ----------------
// frag element (nt, kh, lane, j): n = nt*16+(lane&15), k = kh*32+(lane>>4)*8+j
__global__ void k_wprep(const float* __restrict__ W2, bf16t* __restrict__ W2f) {
    int tt = blockIdx.x * blockDim.x + threadIdx.x;  // 0..1023
    if (tt >= 1024) return;
    int nt = tt >> 7, kh = (tt >> 6) & 1, lane = tt & 63;
    int n = nt * 16 + (lane & 15);
    int k0 = kh * 32 + (lane >> 4) * 8;
    uint4 p;
    p.x = pk2(W2[(k0 + 0) * 128 + n], W2[(k0 + 1) * 128 + n]);
    p.y = pk2(W2[(k0 + 2) * 128 + n], W2[(k0 + 3) * 128 + n]);
    p.z = pk2(W2[(k0 + 4) * 128 + n], W2[(k0 + 5) * 128 + n]);
    p.w = pk2(W2[(k0 + 6) * 128 + n], W2[(k0 + 7) * 128 + n]);
    ((uint4*)W2f)[tt] = p;
}

// ---------------- fused layer-1 agg + dense: quarter-wave per node ----------------
// z = sum_{s in N(n)} xs[s]; h1s[n] = bf16(relu(inv_r*(z@W1 + z9*b1)) * inv_s); warr[n]=z9
__global__ void k_h1f(const unsigned* __restrict__ xs32, const float* __restrict__ W1,
                      const float* __restrict__ b1,
                      const int* __restrict__ csr, const int* __restrict__ cur,
                      const int* __restrict__ degR, const float* __restrict__ inv_r,
                      const float* __restrict__ inv_s,
                      bf16t* __restrict__ h1s, float* __restrict__ warr, int nN) {
    __shared__ float Wl[9 * 64];
    __shared__ float bl[64];
    for (int i = threadIdx.x; i < 9 * 64; i += blockDim.x) Wl[i] = W1[i];
    if (threadIdx.x < 64) bl[threadIdx.x] = b1[threadIdx.x];
    __syncthreads();
    int lane = threadIdx.x & 63;
    int wave = threadIdx.x >> 6;
    int n = blockIdx.x * 16 + wave * 4 + (lane >> 4);
    int qlane = lane & 15;
    int sub = qlane >> 3;   // which edge of the pair
    int f = qlane & 7;      // u32 feature-pair index
    int nc = min(n, nN - 1);
    int deg = degR[nc];
    int st = cur[nc] - deg;
    float2 a0 = make_float2(0.f, 0.f), a1 = make_float2(0.f, 0.f);
    int i = 0;
    for (; i + 4 <= deg; i += 4) {
        int sa = csr[st + i + sub];
        int sb = csr[st + i + 2 + sub];
        unsigned u0 = xs32[(size_t)sa * 8 + f];
        unsigned u1 = xs32[(size_t)sb * 8 + f];
        a0.x += bf2f(u0 & 0xffffu); a0.y += bf2f(u0 >> 16);
        a1.x += bf2f(u1 & 0xffffu); a1.y += bf2f(u1 >> 16);
    }
    for (; i + 2 <= deg; i += 2) {
        unsigned u0 = xs32[(size_t)csr[st + i + sub] * 8 + f];
        a0.x += bf2f(u0 & 0xffffu); a0.y += bf2f(u0 >> 16);
    }
    if (i < deg && sub == 0) {
        unsigned u0 = xs32[(size_t)csr[st + i] * 8 + f];
        a0.x += bf2f(u0 & 0xffffu); a0.y += bf2f(u0 >> 16);
    }
    float2 zp = make_float2(a0.x + a1.x, a0.y + a1.y);
    zp.x += __shfl_xor(zp.x, 8);
    zp.y += __shfl_xor(zp.y, 8);
    // broadcast z[0..9] to all 16 lanes of the quarter-wave
    int base = lane & 48;
    float xv[9];
    xv[0] = __shfl(zp.x, base + 0); xv[1] = __shfl(zp.y, base + 0);
    xv[2] = __shfl(zp.x, base + 1); xv[3] = __shfl(zp.y, base + 1);
    xv[4] = __shfl(zp.x, base + 2); xv[5] = __shfl(zp.y, base + 2);
    xv[6] = __shfl(zp.x, base + 3); xv[7] = __shfl(zp.y, base + 3);
    xv[8] = __shfl(zp.x, base + 4);
    float w = __shfl(zp.y, base + 4);
    float ir = inv_r[nc];
    float is = inv_s[nc];
    int c0 = qlane * 4;
    float acc[4];
#pragma unroll
    for (int j = 0; j < 4; j++) acc[j] = w * bl[c0 + j];
#pragma unroll
    for (int k = 0; k < 9; k++) {
        float4 wv = *(const float4*)(Wl + k * 64 + c0);
        acc[0] += xv[k] * wv.x;
        acc[1] += xv[k] * wv.y;
        acc[2] += xv[k] * wv.z;
        acc[3] += xv[k] * wv.w;
    }
    if (n < nN) {
        float v0 = fmaxf(acc[0] * ir, 0.f) * is;
        float v1 = fmaxf(acc[1] * ir, 0.f) * is;
        float v2 = fmaxf(acc[2] * ir, 0.f) * is;
        float v3 = fmaxf(acc[3] * ir, 0.f) * is;
        uint2 pv;
        pv.x = pk2(v0, v1);
        pv.y = pk2(v2, v3);
        *(uint2*)(h1s + (size_t)n * 64 + c0) = pv;
        if (qlane == 0) warr[n] = w;
    }
}

// ---------------- layer-2 aggregation: wave per node, half-wave per edge, unroll x4 ----------------
// 8 cache lines in flight; output bf16 (feeds MFMA)
__global__ void k_agg64h(const unsigned* __restrict__ h32, unsigned* __restrict__ z32,
                         const int* __restrict__ csr, const int* __restrict__ cur,
                         const int* __restrict__ degR, int nN) {
    int lane = threadIdx.x & 63;
    int wave = threadIdx.x >> 6;
    int n = blockIdx.x * 4 + wave;
    int nc = min(n, nN - 1);
    int hl = lane & 31;
    int sub = lane >> 5;
    int deg = degR[nc];
    int st = cur[nc] - deg;
    float2 s0 = make_float2(0.f, 0.f), s1 = s0, s2 = s0, s3 = s0;
    int i = 0;
    for (; i + 8 <= deg; i += 8) {
        int ea = csr[st + i + sub];
        int eb = csr[st + i + 2 + sub];
        int ec = csr[st + i + 4 + sub];
        int ed = csr[st + i + 6 + sub];
        unsigned u0 = h32[(size_t)ea * 32 + hl];
        unsigned u1 = h32[(size_t)eb * 32 + hl];
        unsigned u2 = h32[(size_t)ec * 32 + hl];
        unsigned u3 = h32[(size_t)ed * 32 + hl];
        s0.x += bf2f(u0 & 0xffffu); s0.y += bf2f(u0 >> 16);
        s1.x += bf2f(u1 & 0xffffu); s1.y += bf2f(u1 >> 16);
        s2.x += bf2f(u2 & 0xffffu); s2.y += bf2f(u2 >> 16);
        s3.x += bf2f(u3 & 0xffffu); s3.y += bf2f(u3 >> 16);
    }
    for (; i + 2 <= deg; i += 2) {
        unsigned u0 = h32[(size_t)csr[st + i + sub] * 32 + hl];
        s0.x += bf2f(u0 & 0xffffu); s0.y += bf2f(u0 >> 16);
    }
    if (i < deg && sub == 0) {
        unsigned u0 = h32[(size_t)csr[st + i] * 32 + hl];
        s0.x += bf2f(u0 & 0xffffu); s0.y += bf2f(u0 >> 16);
    }
    float2 v = make_float2((s0.x + s1.x) + (s2.x + s3.x), (s0.y + s1.y) + (s2.y + s3.y));
    v.x += __shfl_xor(v.x, 32);
    v.y += __shfl_xor(v.y, 32);
    if (sub == 0 && n < nN) z32[(size_t)n * 32 + hl] = pk2(v.x, v.y);
}

// ---------------- fused layers 2+3 via MFMA: t = (relu(inv_r*(z@W2 + w*b2))*inv_s) @ W3 ----------------
// wave = 16 nodes x 128 cols; A frags straight from z (bf16), B frags from W2f (prepped)
__global__ void k_lin23m(const unsigned* __restrict__ z32, const bf16t* __restrict__ W2f,
                         const float* __restrict__ b2, const float* __restrict__ W3,
                         const float* __restrict__ inv_r, const float* __restrict__ inv_s,
                         const float* __restrict__ warr, float* __restrict__ t, int nN) {
    __shared__ float b2l[128];
    __shared__ float W3l[256];
    for (int i = threadIdx.x; i < 128; i += blockDim.x) b2l[i] = b2[i];
    for (int i = threadIdx.x; i < 256; i += blockDim.x) W3l[i] = W3[i];
    __syncthreads();
    int lane = threadIdx.x & 63;
    int wave = threadIdx.x >> 6;
    int n0 = blockIdx.x * 64 + wave * 16;
    int m = lane & 15;
    int q = lane >> 4;
    // A frags: node n0+m, k = kh*32 + q*8 + j
    int na = min(n0 + m, nN - 1);
    short8 afr0 = *(const short8*)(z32 + (size_t)na * 32 + q * 4);
    short8 afr1 = *(const short8*)(z32 + (size_t)na * 32 + 16 + q * 4);
    // per-lane row params (rows q*4+reg, fixed across ntiles)
    float w4[4], ir4[4], is4[4];
#pragma unroll
    for (int reg = 0; reg < 4; reg++) {
        int nr = min(n0 + q * 4 + reg, nN - 1);
        w4[reg] = warr[nr];
        ir4[reg] = inv_r[nr];
        is4[reg] = inv_s[nr];
    }
    float p0[4] = {0.f, 0.f, 0.f, 0.f}, p1[4] = {0.f, 0.f, 0.f, 0.f};
#pragma unroll
    for (int nt = 0; nt < 8; nt++) {
        short8 b0 = *(const short8*)(W2f + ((size_t)(nt * 2 + 0) * 64 + lane) * 8);
        short8 b1 = *(const short8*)(W2f + ((size_t)(nt * 2 + 1) * 64 + lane) * 8);
        f32x4 acc = {0.f, 0.f, 0.f, 0.f};
        acc = __builtin_amdgcn_mfma_f32_16x16x32_bf16(afr0, b0, acc, 0, 0, 0);
        acc = __builtin_amdgcn_mfma_f32_16x16x32_bf16(afr1, b1, acc, 0, 0, 0);
        int col = nt * 16 + m;
        float bc = b2l[col];
        float w30 = W3l[col * 2 + 0];
        float w31 = W3l[col * 2 + 1];
#pragma unroll
        for (int reg = 0; reg < 4; reg++) {
            float h = fmaxf((acc[reg] + w4[reg] * bc) * ir4[reg], 0.f) * is4[reg];
            p0[reg] += h * w30;
            p1[reg] += h * w31;
        }
    }
    // reduce over the 16 col-lanes within each quad
#pragma unroll
    for (int mask = 1; mask < 16; mask <<= 1) {
#pragma unroll
        for (int reg = 0; reg < 4; reg++) {
            p0[reg] += __shfl_xor(p0[reg], mask);
            p1[reg] += __shfl_xor(p1[reg], mask);
        }
    }
    if (m == 0) {
#pragma unroll
        for (int reg = 0; reg < 4; reg++) {
            int nr = n0 + q * 4 + reg;
            if (nr < nN) *(float2*)(t + (size_t)nr * 2) = make_float2(p0[reg], p1[reg]);
        }
    }
}

// ---------------- pooling (node-parallel over CSR) ----------------
__global__ void k_poolg(const float* __restrict__ t, const float* __restrict__ inv_r,
                        const float* __restrict__ warr, const float* __restrict__ b3,
                        const int* __restrict__ csr, const int* __restrict__ cur,
                        const int* __restrict__ degR, const int* __restrict__ batch,
                        float* out, int nN, int outSize) {
    __shared__ float sm[256];
    for (int i = threadIdx.x; i < 256; i += blockDim.x) sm[i] = 0.f;
    __syncthreads();
    int n = blockIdx.x * blockDim.x + threadIdx.x;
    if (n < nN) {
        int deg = degR[n];
        int st = cur[n] - deg;
        float a0 = 0.f, a1 = 0.f, c0 = 0.f, c1 = 0.f;
        int i = 0;
        for (; i + 2 <= deg; i += 2) {
            int sa = csr[st + i], sb = csr[st + i + 1];
            float2 va = ((const float2*)t)[sa];
            float2 vb = ((const float2*)t)[sb];
            a0 += va.x; a1 += va.y;
            c0 += vb.x; c1 += vb.y;
        }
        if (i < deg) {
            float2 va = ((const float2*)t)[csr[st + i]];
            a0 += va.x; a1 += va.y;
        }
        float ir = inv_r[n];
        float wb = warr[n] * ir;
        int g = batch[n];
        atomicAdd(&sm[2 * g + 0], (a0 + c0) * ir + wb * b3[0]);
        atomicAdd(&sm[2 * g + 1], (a1 + c1) * ir + wb * b3[1]);
    }
    __syncthreads();
    for (int i = threadIdx.x; i < outSize; i += blockDim.x) atomicAdd(&out[i], sm[i]);
}

extern "C" void kernel_launch(void* const* d_in, const int* in_sizes, int n_in,
                              void* d_out, int out_size, void* d_ws, size_t ws_size,
                              hipStream_t stream) {
    const float* x     = (const float*)d_in[0];
    const int*   S     = (const int*)d_in[1];
    const int*   R     = (const int*)d_in[2];
    const int*   batch = (const int*)d_in[3];
    const float* W1 = (const float*)d_in[5];
    const float* b1 = (const float*)d_in[6];
    const float* W2 = (const float*)d_in[7];
    const float* b2 = (const float*)d_in[8];
    const float* W3 = (const float*)d_in[9];
    const float* b3 = (const float*)d_in[10];

    int nN = in_sizes[0] / 9;
    int nE = in_sizes[1];
    int nB = (nN + 511) / 512;  // buckets of 512 nodes; requires nB <= 256

    char* ws = (char*)d_ws;
    int*   cur   = (int*)ws;                          // nN
    int*   degR  = cur + nN;                          // nN
    float* inv_s = (float*)(degR + nN);               // nN
    float* inv_r = inv_s + nN;                        // nN
    float* warr  = inv_r + nN;                        // nN
    int*   gCntR = (int*)(warr + nN);                 // 256
    int*   gCntS = gCntR + 256;                       // 256
    int*   csr   = gCntS + 256;                       // nE
    bf16t* xs    = (bf16t*)(csr + nE);                // nN*16 bf16 (3.2 MB)
    bf16t* W2f   = xs + (size_t)nN * 16;              // 8192 bf16 (16 KB)
    float* regA  = (float*)(W2f + 8192);              // big region
    // aliasing (lifetimes disjoint; bufR/bufS dead after k_pass2):
    unsigned*       bufR = (unsigned*)regA;                       // 256*BCAP u32 = 12.6 MB
    unsigned short* bufS = (unsigned short*)(bufR + 256 * BCAP);  // 6.3 MB
    bf16t*    h1s = (bf16t*)regA;                     // nN*64 bf16 (12.8 MB)
    unsigned* z32 = (unsigned*)(h1s + (size_t)nN * 64);  // nN*32 u32 (12.8 MB)
    float*    t   = (float*)(z32 + (size_t)nN * 32);  // nN*2 fp32

    const int B = 256;
    int gN = (nN + B - 1) / B;

    // ---- CSR + degrees + inv_s + xs via fused bucket sort; W2 frag prep ----
    hipMemsetAsync(gCntR, 0, 512 * 4, stream);
    k_wprep<<<4, B, 0, stream>>>(W2, W2f);
    k_bucket<<<256, B, 0, stream>>>(S, R, bufR, bufS, gCntR, gCntS, nE, nB);
    k_pass2<<<nB, B, 0, stream>>>(bufR, bufS, gCntR, gCntS, x, csr, cur, degR,
                                  inv_r, inv_s, xs, nN, nB);

    // ---- layer 1: fused gather + 9->64 dense (quarter-wave per node) ----
    k_h1f<<<(nN + 15) / 16, B, 0, stream>>>((const unsigned*)xs, W1, b1, csr, cur, degR,
                                            inv_r, inv_s, h1s, warr, nN);

    // ---- layer 2: gather (half-wave per edge, bf16 out), fused MFMA 64->128->2 ----
    k_agg64h<<<(nN + 3) / 4, B, 0, stream>>>((const unsigned*)h1s, z32, csr, cur, degR, nN);
    k_lin23m<<<(nN + 63) / 64, B, 0, stream>>>(z32, W2f, b2, W3, inv_r, inv_s, warr, t, nN);

    // ---- fused layer-3 aggregation + bias + pooling ----
    hipMemsetAsync(d_out, 0, (size_t)out_size * 4, stream);
    k_poolg<<<gN, B, 0, stream>>>(t, inv_r, warr, b3, csr, cur, degR, batch,
                                  (float*)d_out, nN, out_size);
}

// Round 8
// 243.281 us; speedup vs baseline: 8.9664x; 1.0604x over previous
//
#include <hip/hip_runtime.h>
#include <hip/hip_bf16.h>
#include <cstddef>

#define BCAP 12288  // per-bucket capacity; mean ~8184, sigma ~90
#define BKCHUNK 3200  // max edges per bucket-sort block (grid 512 -> 3125)

typedef unsigned short bf16t;
typedef __attribute__((ext_vector_type(8))) short short8;
typedef __attribute__((ext_vector_type(4))) float f32x4;

static __device__ __forceinline__ float bf2f(unsigned h16) {
    return __uint_as_float(h16 << 16);
}
static __device__ __forceinline__ float2 up2(unsigned u) {
    return make_float2(__uint_as_float(u << 16), __uint_as_float(u & 0xffff0000u));
}
static __device__ __forceinline__ bf16t f2bf(float f) {
    unsigned u = __float_as_uint(f);
    u += 0x7fffu + ((u >> 16) & 1u);  // round-to-nearest-even (finite values)
    return (bf16t)(u >> 16);
}
static __device__ __forceinline__ unsigned pk2(float a, float b) {
    return (unsigned)f2bf(a) | ((unsigned)f2bf(b) << 16);
}

// ---------------- pass 1: bucket edges by receiver AND sender ----------------
// LDS counting-sort per block -> coalesced bucket-stream writes
__global__ void k_bucket(const int* __restrict__ S, const int* __restrict__ R,
                         unsigned* __restrict__ bufR, unsigned short* __restrict__ bufS,
                         int* __restrict__ gCntR, int* __restrict__ gCntS,
                         int nE, int nB) {
    __shared__ int histR[256], lstR[256], baseR[256];
    __shared__ int histS[256], lstS[256], baseS[256];
    __shared__ int sm[256];
    __shared__ unsigned sortedR[BKCHUNK];
    __shared__ unsigned short sortedS[BKCHUNK];
    __shared__ unsigned char bOfR[BKCHUNK], bOfS[BKCHUNK];
    int t = threadIdx.x;
    histR[t] = 0; histS[t] = 0;
    __syncthreads();
    int chunk = (nE + gridDim.x - 1) / gridDim.x;
    int e0 = blockIdx.x * chunk;
    int e1 = min(e0 + chunk, nE);
    for (int e = e0 + t; e < e1; e += blockDim.x) {
        atomicAdd(&histR[R[e] >> 9], 1);
        atomicAdd(&histS[S[e] >> 9], 1);
    }
    __syncthreads();
    int vR = histR[t], vS = histS[t];
    // local exclusive scan (R)
    sm[t] = vR;
    __syncthreads();
    for (int off = 1; off < 256; off <<= 1) {
        int y = (t >= off) ? sm[t - off] : 0;
        __syncthreads();
        sm[t] += y;
        __syncthreads();
    }
    lstR[t] = sm[t] - vR;
    __syncthreads();
    // local exclusive scan (S)
    sm[t] = vS;
    __syncthreads();
    for (int off = 1; off < 256; off <<= 1) {
        int y = (t >= off) ? sm[t - off] : 0;
        __syncthreads();
        sm[t] += y;
        __syncthreads();
    }
    lstS[t] = sm[t] - vS;
    // global reservation
    if (t < nB) {
        baseR[t] = vR ? atomicAdd(&gCntR[t], vR) : 0;
        baseS[t] = vS ? atomicAdd(&gCntS[t], vS) : 0;
    }
    histR[t] = 0; histS[t] = 0;  // reuse as local cursors
    __syncthreads();
    // scatter into LDS, sorted by bucket
    for (int e = e0 + t; e < e1; e += blockDim.x) {
        int r = R[e], s = S[e];
        int br = r >> 9;
        int p = lstR[br] + atomicAdd(&histR[br], 1);
        sortedR[p] = ((unsigned)(r & 511) << 23) | (unsigned)s;
        bOfR[p] = (unsigned char)br;
        int bs = s >> 9;
        int p2 = lstS[bs] + atomicAdd(&histS[bs], 1);
        sortedS[p2] = (unsigned short)(s & 511);
        bOfS[p2] = (unsigned char)bs;
    }
    __syncthreads();
    // coalesced flush (runs of ~16 consecutive slots per bucket)
    int cnt = e1 - e0;
    for (int i = t; i < cnt; i += blockDim.x) {
        int b = bOfR[i];
        int slot = baseR[b] + (i - lstR[b]);
        if (slot < BCAP) bufR[(size_t)b * BCAP + slot] = sortedR[i];
        int b2 = bOfS[i];
        int slot2 = baseS[b2] + (i - lstS[b2]);
        if (slot2 < BCAP) bufS[(size_t)b2 * BCAP + slot2] = sortedS[i];
    }
}

// ---------------- pass 2 (fused): per-bucket CSR + degR/inv_r + inv_s + xs prep ----------------
__global__ void k_pass2(const unsigned* __restrict__ bufR, const unsigned short* __restrict__ bufS,
                        const int* __restrict__ gCntR, const int* __restrict__ gCntS,
                        const float* __restrict__ x,
                        int* __restrict__ csr, int* __restrict__ cur, int* __restrict__ degR,
                        float* __restrict__ inv_r, float* __restrict__ inv_s,
                        bf16t* __restrict__ xs, int nN, int nB) {
    __shared__ int hist[512];
    __shared__ int incl[512];
    __shared__ int curs[512];
    __shared__ int sm[256];
    __shared__ int histS[512];
    int t = threadIdx.x;
    int b = blockIdx.x;
    int v = (t < nB) ? gCntR[t] : 0;
    sm[t] = v;
    __syncthreads();
    for (int off = 1; off < 256; off <<= 1) {
        int y = (t >= off) ? sm[t - off] : 0;
        __syncthreads();
        sm[t] += y;
        __syncthreads();
    }
    int gb = (b == 0) ? 0 : sm[b - 1];
    int cnt = gCntR[b];
    __syncthreads();

    const unsigned* buf = bufR + (size_t)b * BCAP;
    for (int i = t; i < 512; i += blockDim.x) { hist[i] = 0; curs[i] = 0; histS[i] = 0; }
    __syncthreads();
    for (int i = t; i < cnt; i += blockDim.x)
        atomicAdd(&hist[buf[i] >> 23], 1);
    __syncthreads();
    int a0 = hist[2 * t], a1 = hist[2 * t + 1];
    int ps = a0 + a1;
    sm[t] = ps;
    __syncthreads();
    for (int off = 1; off < 256; off <<= 1) {
        int y = (t >= off) ? sm[t - off] : 0;
        __syncthreads();
        sm[t] += y;
        __syncthreads();
    }
    int ex = sm[t] - ps;
    incl[2 * t] = ex + a0;
    incl[2 * t + 1] = ex + a0 + a1;
    __syncthreads();
    int n0 = b << 9;
    for (int i = t; i < 512; i += blockDim.x) {
        int n = n0 + i;
        if (n < nN) {
            int d = hist[i];
            degR[n] = d;
            cur[n] = gb + incl[i];  // end offset (agg kernels use cur-deg)
            inv_r[n] = rsqrtf(fmaxf((float)d, 1.f));
        }
    }
    for (int i = t; i < cnt; i += blockDim.x) {
        unsigned p = buf[i];
        int rl = p >> 23;
        int s = p & 0x7FFFFF;
        int pos = gb + (incl[rl] - hist[rl]) + atomicAdd(&curs[rl], 1);
        csr[pos] = s;
    }
    // ---- sender part: out-degree -> inv_s, + xs prep (bf16) ----
    int cntS = gCntS[b];
    const unsigned short* bufs = bufS + (size_t)b * BCAP;
    for (int i = t; i < cntS; i += blockDim.x)
        atomicAdd(&histS[bufs[i]], 1);
    __syncthreads();
    for (int i = t; i < 512; i += blockDim.x) {
        int n = n0 + i;
        if (n < nN) {
            float is = rsqrtf(fmaxf((float)histS[i], 1.f));
            inv_s[n] = is;
            float w[9];
#pragma unroll
            for (int k = 0; k < 9; k++) w[k] = x[(size_t)n * 9 + k] * is;
            uint4 pa, pb;
            pa.x = pk2(w[0], w[1]); pa.y = pk2(w[2], w[3]);
            pa.z = pk2(w[4], w[5]); pa.w = pk2(w[6], w[7]);
            pb.x = pk2(w[8], is);   pb.y = 0; pb.z = 0; pb.w = 0;
            uint4* o = (uint4*)(xs + (size_t)n * 16);
            o[0] = pa;
            o[1] = pb;
        }
    }
}

// ---------------- W2 -> B-fragment prep (bf16, MFMA B^T frag layout) ----------------
__global__ void k_wprep(const float* __restrict__ W2, bf16t* __restrict__ W2f) {
    int tt = blockIdx.x * blockDim.x + threadIdx.x;  // 0..1023
    if (tt >= 1024) return;
    int nt = tt >> 7, kh = (tt >> 6) & 1, lane = tt & 63;
    int n = nt * 16 + (lane & 15);
    int k0 = kh * 32 + (lane >> 4) * 8;
    uint4 p;
    p.x = pk2(W2[(k0 + 0) * 128 + n], W2[(k0 + 1) * 128 + n]);
    p.y = pk2(W2[(k0 + 2) * 128 + n], W2[(k0 + 3) * 128 + n]);
    p.z = pk2(W2[(k0 + 4) * 128 + n], W2[(k0 + 5) * 128 + n]);
    p.w = pk2(W2[(k0 + 6) * 128 + n], W2[(k0 + 7) * 128 + n]);
    ((uint4*)W2f)[tt] = p;
}

// ---------------- fused layer-1 agg + dense: quarter-wave per node, 4 lanes per edge ----------------
__global__ void k_h1f(const unsigned* __restrict__ xs32, const float* __restrict__ W1,
                      const float* __restrict__ b1,
                      const int* __restrict__ csr, const int* __restrict__ cur,
                      const int* __restrict__ degR, const float* __restrict__ inv_r,
                      const float* __restrict__ inv_s,
                      bf16t* __restrict__ h1s, float* __restrict__ warr, int nN) {
    __shared__ float Wl[9 * 64];
    __shared__ float bl[64];
    for (int i = threadIdx.x; i < 9 * 64; i += blockDim.x) Wl[i] = W1[i];
    if (threadIdx.x < 64) bl[threadIdx.x] = b1[threadIdx.x];
    __syncthreads();
    int lane = threadIdx.x & 63;
    int wave = threadIdx.x >> 6;
    int n = blockIdx.x * 16 + wave * 4 + (lane >> 4);
    int ql = lane & 15;
    int g = ql >> 2;      // edge slot within quarter (4 edges in parallel)
    int f2 = ql & 3;      // uint2 index into the 32B xs row
    int nc = min(n, nN - 1);
    int deg = degR[nc];
    int st = cur[nc] - deg;
    float4 A0 = {0.f, 0.f, 0.f, 0.f}, A1 = {0.f, 0.f, 0.f, 0.f};
    int i = 0;
    for (; i + 8 <= deg; i += 8) {
        int ea = csr[st + i + g];
        int eb = csr[st + i + 4 + g];
        uint2 u0 = *(const uint2*)(xs32 + (size_t)ea * 8 + f2 * 2);
        uint2 u1 = *(const uint2*)(xs32 + (size_t)eb * 8 + f2 * 2);
        float2 l0 = up2(u0.x), h0 = up2(u0.y), l1 = up2(u1.x), h1 = up2(u1.y);
        A0.x += l0.x; A0.y += l0.y; A0.z += h0.x; A0.w += h0.y;
        A1.x += l1.x; A1.y += l1.y; A1.z += h1.x; A1.w += h1.y;
    }
    for (; i + 4 <= deg; i += 4) {
        int ea = csr[st + i + g];
        uint2 u0 = *(const uint2*)(xs32 + (size_t)ea * 8 + f2 * 2);
        float2 l0 = up2(u0.x), h0 = up2(u0.y);
        A0.x += l0.x; A0.y += l0.y; A0.z += h0.x; A0.w += h0.y;
    }
    if (g < deg - i) {
        int ea = csr[st + i + g];
        uint2 u0 = *(const uint2*)(xs32 + (size_t)ea * 8 + f2 * 2);
        float2 l0 = up2(u0.x), h0 = up2(u0.y);
        A1.x += l0.x; A1.y += l0.y; A1.z += h0.x; A1.w += h0.y;
    }
    float4 vq = {A0.x + A1.x, A0.y + A1.y, A0.z + A1.z, A0.w + A1.w};
    // reduce across the 4 g-groups (xor 4, 8 stay within the 16-lane quarter)
    vq.x += __shfl_xor(vq.x, 4); vq.y += __shfl_xor(vq.y, 4);
    vq.z += __shfl_xor(vq.z, 4); vq.w += __shfl_xor(vq.w, 4);
    vq.x += __shfl_xor(vq.x, 8); vq.y += __shfl_xor(vq.y, 8);
    vq.z += __shfl_xor(vq.z, 8); vq.w += __shfl_xor(vq.w, 8);
    // broadcast z[0..9] to all 16 lanes (feat k held by lane base+(k>>2), comp k&3)
    int base = lane & 48;
    float xv[9];
    xv[0] = __shfl(vq.x, base + 0); xv[1] = __shfl(vq.y, base + 0);
    xv[2] = __shfl(vq.z, base + 0); xv[3] = __shfl(vq.w, base + 0);
    xv[4] = __shfl(vq.x, base + 1); xv[5] = __shfl(vq.y, base + 1);
    xv[6] = __shfl(vq.z, base + 1); xv[7] = __shfl(vq.w, base + 1);
    xv[8] = __shfl(vq.x, base + 2);
    float w = __shfl(vq.y, base + 2);
    float ir = inv_r[nc];
    float is = inv_s[nc];
    int c0 = ql * 4;
    float acc[4];
#pragma unroll
    for (int j = 0; j < 4; j++) acc[j] = w * bl[c0 + j];
#pragma unroll
    for (int k = 0; k < 9; k++) {
        float4 wv = *(const float4*)(Wl + k * 64 + c0);
        acc[0] += xv[k] * wv.x;
        acc[1] += xv[k] * wv.y;
        acc[2] += xv[k] * wv.z;
        acc[3] += xv[k] * wv.w;
    }
    if (n < nN) {
        float v0 = fmaxf(acc[0] * ir, 0.f) * is;
        float v1 = fmaxf(acc[1] * ir, 0.f) * is;
        float v2 = fmaxf(acc[2] * ir, 0.f) * is;
        float v3 = fmaxf(acc[3] * ir, 0.f) * is;
        uint2 pv;
        pv.x = pk2(v0, v1);
        pv.y = pk2(v2, v3);
        *(uint2*)(h1s + (size_t)n * 64 + c0) = pv;
        if (ql == 0) warr[n] = w;
    }
}

// ---------------- layer-2 aggregation: wave per node, quarter-wave per edge, unroll x4 ----------------
// 16 cache lines in flight per wave
__global__ void k_agg64h(const unsigned* __restrict__ h32, unsigned* __restrict__ z32,
                         const int* __restrict__ csr, const int* __restrict__ cur,
                         const int* __restrict__ degR, int nN) {
    int lane = threadIdx.x & 63;
    int wave = threadIdx.x >> 6;
    int n = blockIdx.x * 4 + wave;
    int nc = min(n, nN - 1);
    int q = lane >> 4;    // edge slot (4 edges in parallel)
    int ql = lane & 15;   // uint2 index into the 128B row
    int deg = degR[nc];
    int st = cur[nc] - deg;
    float4 A0 = {0.f, 0.f, 0.f, 0.f}, A1 = A0, A2 = A0, A3 = A0;
    int i = 0;
    for (; i + 16 <= deg; i += 16) {
        int ea = csr[st + i + q];
        int eb = csr[st + i + 4 + q];
        int ec = csr[st + i + 8 + q];
        int ed = csr[st + i + 12 + q];
        uint2 u0 = *(const uint2*)(h32 + (size_t)ea * 32 + ql * 2);
        uint2 u1 = *(const uint2*)(h32 + (size_t)eb * 32 + ql * 2);
        uint2 u2 = *(const uint2*)(h32 + (size_t)ec * 32 + ql * 2);
        uint2 u3 = *(const uint2*)(h32 + (size_t)ed * 32 + ql * 2);
        float2 a = up2(u0.x), b = up2(u0.y);
        A0.x += a.x; A0.y += a.y; A0.z += b.x; A0.w += b.y;
        a = up2(u1.x); b = up2(u1.y);
        A1.x += a.x; A1.y += a.y; A1.z += b.x; A1.w += b.y;
        a = up2(u2.x); b = up2(u2.y);
        A2.x += a.x; A2.y += a.y; A2.z += b.x; A2.w += b.y;
        a = up2(u3.x); b = up2(u3.y);
        A3.x += a.x; A3.y += a.y; A3.z += b.x; A3.w += b.y;
    }
    for (; i + 4 <= deg; i += 4) {
        int ea = csr[st + i + q];
        uint2 u0 = *(const uint2*)(h32 + (size_t)ea * 32 + ql * 2);
        float2 a = up2(u0.x), b = up2(u0.y);
        A0.x += a.x; A0.y += a.y; A0.z += b.x; A0.w += b.y;
    }
    if (q < deg - i) {
        int ea = csr[st + i + q];
        uint2 u0 = *(const uint2*)(h32 + (size_t)ea * 32 + ql * 2);
        float2 a = up2(u0.x), b = up2(u0.y);
        A1.x += a.x; A1.y += a.y; A1.z += b.x; A1.w += b.y;
    }
    float4 v = {(A0.x + A1.x) + (A2.x + A3.x), (A0.y + A1.y) + (A2.y + A3.y),
                (A0.z + A1.z) + (A2.z + A3.z), (A0.w + A1.w) + (A2.w + A3.w)};
    // reduce across the 4 quarters
    v.x += __shfl_xor(v.x, 16); v.y += __shfl_xor(v.y, 16);
    v.z += __shfl_xor(v.z, 16); v.w += __shfl_xor(v.w, 16);
    v.x += __shfl_xor(v.x, 32); v.y += __shfl_xor(v.y, 32);
    v.z += __shfl_xor(v.z, 32); v.w += __shfl_xor(v.w, 32);
    if (q == 0 && n < nN) {
        uint2 pv;
        pv.x = pk2(v.x, v.y);
        pv.y = pk2(v.z, v.w);
        *(uint2*)(z32 + (size_t)n * 32 + ql * 2) = pv;
    }
}

// ---------------- fused layers 2+3 via MFMA: t = (relu(inv_r*(z@W2 + w*b2))*inv_s) @ W3 ----------------
__global__ void k_lin23m(const unsigned* __restrict__ z32, const bf16t* __restrict__ W2f,
                         const float* __restrict__ b2, const float* __restrict__ W3,
                         const float* __restrict__ inv_r, const float* __restrict__ inv_s,
                         const float* __restrict__ warr, float* __restrict__ t, int nN) {
    __shared__ float b2l[128];
    __shared__ float W3l[256];
    for (int i = threadIdx.x; i < 128; i += blockDim.x) b2l[i] = b2[i];
    for (int i = threadIdx.x; i < 256; i += blockDim.x) W3l[i] = W3[i];
    __syncthreads();
    int lane = threadIdx.x & 63;
    int wave = threadIdx.x >> 6;
    int n0 = blockIdx.x * 64 + wave * 16;
    int m = lane & 15;
    int q = lane >> 4;
    int na = min(n0 + m, nN - 1);
    short8 afr0 = *(const short8*)(z32 + (size_t)na * 32 + q * 4);
    short8 afr1 = *(const short8*)(z32 + (size_t)na * 32 + 16 + q * 4);
    float w4[4], ir4[4], is4[4];
#pragma unroll
    for (int reg = 0; reg < 4; reg++) {
        int nr = min(n0 + q * 4 + reg, nN - 1);
        w4[reg] = warr[nr];
        ir4[reg] = inv_r[nr];
        is4[reg] = inv_s[nr];
    }
    float p0[4] = {0.f, 0.f, 0.f, 0.f}, p1[4] = {0.f, 0.f, 0.f, 0.f};
#pragma unroll
    for (int nt = 0; nt < 8; nt++) {
        short8 b0 = *(const short8*)(W2f + ((size_t)(nt * 2 + 0) * 64 + lane) * 8);
        short8 b1 = *(const short8*)(W2f + ((size_t)(nt * 2 + 1) * 64 + lane) * 8);
        f32x4 acc = {0.f, 0.f, 0.f, 0.f};
        acc = __builtin_amdgcn_mfma_f32_16x16x32_bf16(afr0, b0, acc, 0, 0, 0);
        acc = __builtin_amdgcn_mfma_f32_16x16x32_bf16(afr1, b1, acc, 0, 0, 0);
        int col = nt * 16 + m;
        float bc = b2l[col];
        float w30 = W3l[col * 2 + 0];
        float w31 = W3l[col * 2 + 1];
#pragma unroll
        for (int reg = 0; reg < 4; reg++) {
            float h = fmaxf((acc[reg] + w4[reg] * bc) * ir4[reg], 0.f) * is4[reg];
            p0[reg] += h * w30;
            p1[reg] += h * w31;
        }
    }
#pragma unroll
    for (int mask = 1; mask < 16; mask <<= 1) {
#pragma unroll
        for (int reg = 0; reg < 4; reg++) {
            p0[reg] += __shfl_xor(p0[reg], mask);
            p1[reg] += __shfl_xor(p1[reg], mask);
        }
    }
    if (m == 0) {
#pragma unroll
        for (int reg = 0; reg < 4; reg++) {
            int nr = n0 + q * 4 + reg;
            if (nr < nN) *(float2*)(t + (size_t)nr * 2) = make_float2(p0[reg], p1[reg]);
        }
    }
}

// ---------------- pooling (node-parallel over CSR), unroll x4 ----------------
__global__ void k_poolg(const float* __restrict__ t, const float* __restrict__ inv_r,
                        const float* __restrict__ warr, const float* __restrict__ b3,
                        const int* __restrict__ csr, const int* __restrict__ cur,
                        const int* __restrict__ degR, const int* __restrict__ batch,
                        float* out, int nN, int outSize) {
    __shared__ float sm[256];
    for (int i = threadIdx.x; i < 256; i += blockDim.x) sm[i] = 0.f;
    __syncthreads();
    float b30 = b3[0], b31 = b3[1];
    int n = blockIdx.x * blockDim.x + threadIdx.x;
    if (n < nN) {
        int deg = degR[n];
        int st = cur[n] - deg;
        float a0 = 0.f, a1 = 0.f, c0 = 0.f, c1 = 0.f;
        float d0 = 0.f, d1 = 0.f, e0 = 0.f, e1 = 0.f;
        int i = 0;
        for (; i + 4 <= deg; i += 4) {
            int sa = csr[st + i], sb = csr[st + i + 1];
            int sc = csr[st + i + 2], sd = csr[st + i + 3];
            float2 va = ((const float2*)t)[sa];
            float2 vb = ((const float2*)t)[sb];
            float2 vc = ((const float2*)t)[sc];
            float2 vd = ((const float2*)t)[sd];
            a0 += va.x; a1 += va.y;
            c0 += vb.x; c1 += vb.y;
            d0 += vc.x; d1 += vc.y;
            e0 += vd.x; e1 += vd.y;
        }
        for (; i < deg; i++) {
            float2 va = ((const float2*)t)[csr[st + i]];
            a0 += va.x; a1 += va.y;
        }
        float ir = inv_r[n];
        float wb = warr[n] * ir;
        int g = batch[n];
        atomicAdd(&sm[2 * g + 0], ((a0 + c0) + (d0 + e0)) * ir + wb * b30);
        atomicAdd(&sm[2 * g + 1], ((a1 + c1) + (d1 + e1)) * ir + wb * b31);
    }
    __syncthreads();
    for (int i = threadIdx.x; i < outSize; i += blockDim.x) atomicAdd(&out[i], sm[i]);
}

extern "C" void kernel_launch(void* const* d_in, const int* in_sizes, int n_in,
                              void* d_out, int out_size, void* d_ws, size_t ws_size,
                              hipStream_t stream) {
    const float* x     = (const float*)d_in[0];
    const int*   S     = (const int*)d_in[1];
    const int*   R     = (const int*)d_in[2];
    const int*   batch = (const int*)d_in[3];
    const float* W1 = (const float*)d_in[5];
    const float* b1 = (const float*)d_in[6];
    const float* W2 = (const float*)d_in[7];
    const float* b2 = (const float*)d_in[8];
    const float* W3 = (const float*)d_in[9];
    const float* b3 = (const float*)d_in[10];

    int nN = in_sizes[0] / 9;
    int nE = in_sizes[1];
    int nB = (nN + 511) / 512;  // buckets of 512 nodes; requires nB <= 256

    char* ws = (char*)d_ws;
    int*   cur   = (int*)ws;                          // nN
    int*   degR  = cur + nN;                          // nN
    float* inv_s = (float*)(degR + nN);               // nN
    float* inv_r = inv_s + nN;                        // nN
    float* warr  = inv_r + nN;                        // nN
    int*   gCntR = (int*)(warr + nN);                 // 256
    int*   gCntS = gCntR + 256;                       // 256
    int*   csr   = gCntS + 256;                       // nE
    bf16t* xs    = (bf16t*)(csr + nE);                // nN*16 bf16 (3.2 MB)
    bf16t* W2f   = xs + (size_t)nN * 16;              // 8192 bf16 (16 KB)
    float* regA  = (float*)(W2f + 8192);              // big region
    unsigned*       bufR = (unsigned*)regA;                       // 256*BCAP u32 = 12.6 MB
    unsigned short* bufS = (unsigned short*)(bufR + 256 * BCAP);  // 6.3 MB
    bf16t*    h1s = (bf16t*)regA;                     // nN*64 bf16 (12.8 MB)
    unsigned* z32 = (unsigned*)(h1s + (size_t)nN * 64);  // nN*32 u32 (12.8 MB)
    float*    t   = (float*)(z32 + (size_t)nN * 32);  // nN*2 fp32

    const int B = 256;
    int gN = (nN + B - 1) / B;

    // ---- CSR + degrees + inv_s + xs via fused bucket sort; W2 frag prep ----
    hipMemsetAsync(gCntR, 0, 512 * 4, stream);
    k_wprep<<<4, B, 0, stream>>>(W2, W2f);
    k_bucket<<<512, B, 0, stream>>>(S, R, bufR, bufS, gCntR, gCntS, nE, nB);
    k_pass2<<<nB, B, 0, stream>>>(bufR, bufS, gCntR, gCntS, x, csr, cur, degR,
                                  inv_r, inv_s, xs, nN, nB);

    // ---- layer 1: fused gather + 9->64 dense ----
    k_h1f<<<(nN + 15) / 16, B, 0, stream>>>((const unsigned*)xs, W1, b1, csr, cur, degR,
                                            inv_r, inv_s, h1s, warr, nN);

    // ---- layer 2: gather (quarter-wave per edge, 16 lines in flight), fused MFMA 64->128->2 ----
    k_agg64h<<<(nN + 3) / 4, B, 0, stream>>>((const unsigned*)h1s, z32, csr, cur, degR, nN);
    k_lin23m<<<(nN + 63) / 64, B, 0, stream>>>(z32, W2f, b2, W3, inv_r, inv_s, warr, t, nN);

    // ---- fused layer-3 aggregation + bias + pooling ----
    hipMemsetAsync(d_out, 0, (size_t)out_size * 4, stream);
    k_poolg<<<gN, B, 0, stream>>>(t, inv_r, warr, b3, csr, cur, degR, batch,
                                  (float*)d_out, nN, out_size);
}

// Round 9
// 229.742 us; speedup vs baseline: 9.4948x; 1.0589x over previous
//
#include <hip/hip_runtime.h>
#include <hip/hip_bf16.h>
#include <cstddef>

#define NBMAX 512     // max buckets (256 nodes each -> supports nN <= 131072)
#define BCAP 5120     // per-bucket edge capacity; mean ~4092, sigma ~64 (16-sigma headroom)
#define BKCHUNK 3200  // max edges per bucket-sort block (512 sort blocks -> 3125)

typedef unsigned short bf16t;
typedef __attribute__((ext_vector_type(8))) short short8;
typedef __attribute__((ext_vector_type(4))) float f32x4;

static __device__ __forceinline__ float2 up2(unsigned u) {
    return make_float2(__uint_as_float(u << 16), __uint_as_float(u & 0xffff0000u));
}
static __device__ __forceinline__ bf16t f2bf(float f) {
    unsigned u = __float_as_uint(f);
    u += 0x7fffu + ((u >> 16) & 1u);  // round-to-nearest-even (finite values)
    return (bf16t)(u >> 16);
}
static __device__ __forceinline__ unsigned pk2(float a, float b) {
    return (unsigned)f2bf(a) | ((unsigned)f2bf(b) << 16);
}

// ---------------- pass 1: LDS counting-sort of edges into receiver/sender buckets ----------------
// R entry = (r&255)<<24 | s ; S entry = s&255 (u8). Last 4 blocks do W2-fragment prep.
__global__ void k_bucket(const int* __restrict__ S, const int* __restrict__ R,
                         unsigned* __restrict__ bufR, unsigned char* __restrict__ bufS,
                         int* __restrict__ gCntR, int* __restrict__ gCntS,
                         const float* __restrict__ W2, bf16t* __restrict__ W2f,
                         int nE, int nB) {
    __shared__ int histR[NBMAX], lstR[NBMAX], baseR[NBMAX];
    __shared__ int histS[NBMAX], lstS[NBMAX], baseS[NBMAX];
    __shared__ int sm[256];
    __shared__ unsigned sortedR[BKCHUNK];
    __shared__ unsigned short bOfR[BKCHUNK];
    __shared__ unsigned char sortedS[BKCHUNK];
    __shared__ unsigned short bOfS[BKCHUNK];
    int t = threadIdx.x;
    int nSort = gridDim.x - 4;
    if (blockIdx.x >= nSort) {
        // ---- W2 -> MFMA B^T fragment prep: n = nt*16+(lane&15), k = kh*32+(lane>>4)*8+j ----
        int tt = (blockIdx.x - nSort) * blockDim.x + t;
        if (tt < 1024) {
            int nt = tt >> 7, kh = (tt >> 6) & 1, lane = tt & 63;
            int n = nt * 16 + (lane & 15);
            int k0 = kh * 32 + (lane >> 4) * 8;
            uint4 p;
            p.x = pk2(W2[(k0 + 0) * 128 + n], W2[(k0 + 1) * 128 + n]);
            p.y = pk2(W2[(k0 + 2) * 128 + n], W2[(k0 + 3) * 128 + n]);
            p.z = pk2(W2[(k0 + 4) * 128 + n], W2[(k0 + 5) * 128 + n]);
            p.w = pk2(W2[(k0 + 6) * 128 + n], W2[(k0 + 7) * 128 + n]);
            ((uint4*)W2f)[tt] = p;
        }
        return;
    }
    for (int i = t; i < NBMAX; i += 256) { histR[i] = 0; histS[i] = 0; }
    __syncthreads();
    int chunk = (nE + nSort - 1) / nSort;
    int e0 = blockIdx.x * chunk;
    int e1 = min(e0 + chunk, nE);
    for (int e = e0 + t; e < e1; e += 256) {
        atomicAdd(&histR[R[e] >> 8], 1);
        atomicAdd(&histS[S[e] >> 8], 1);
    }
    __syncthreads();
    // local exclusive scan over 512 bins (pairwise + Hillis-Steele), R then S
    {
        int c0 = histR[2 * t], c1 = histR[2 * t + 1];
        int ps = c0 + c1;
        sm[t] = ps;
        __syncthreads();
        for (int off = 1; off < 256; off <<= 1) {
            int y = (t >= off) ? sm[t - off] : 0;
            __syncthreads();
            sm[t] += y;
            __syncthreads();
        }
        int ex = sm[t] - ps;
        lstR[2 * t] = ex;
        lstR[2 * t + 1] = ex + c0;
    }
    __syncthreads();
    {
        int c0 = histS[2 * t], c1 = histS[2 * t + 1];
        int ps = c0 + c1;
        sm[t] = ps;
        __syncthreads();
        for (int off = 1; off < 256; off <<= 1) {
            int y = (t >= off) ? sm[t - off] : 0;
            __syncthreads();
            sm[t] += y;
            __syncthreads();
        }
        int ex = sm[t] - ps;
        lstS[2 * t] = ex;
        lstS[2 * t + 1] = ex + c0;
    }
    __syncthreads();
    // global space reservation
    for (int i = t; i < nB; i += 256) {
        int cR = histR[i];
        baseR[i] = cR ? atomicAdd(&gCntR[i], cR) : 0;
        int cS = histS[i];
        baseS[i] = cS ? atomicAdd(&gCntS[i], cS) : 0;
    }
    for (int i = t; i < NBMAX; i += 256) { histR[i] = 0; histS[i] = 0; }  // reuse as cursors
    __syncthreads();
    // scatter into LDS, sorted by bucket
    for (int e = e0 + t; e < e1; e += 256) {
        int r = R[e], s = S[e];
        int br = r >> 8;
        int p = lstR[br] + atomicAdd(&histR[br], 1);
        sortedR[p] = ((unsigned)(r & 255) << 24) | (unsigned)s;
        bOfR[p] = (unsigned short)br;
        int bs = s >> 8;
        int p2 = lstS[bs] + atomicAdd(&histS[bs], 1);
        sortedS[p2] = (unsigned char)(s & 255);
        bOfS[p2] = (unsigned short)bs;
    }
    __syncthreads();
    // coalesced flush
    int cnt = e1 - e0;
    for (int i = t; i < cnt; i += 256) {
        int b = bOfR[i];
        int slot = baseR[b] + (i - lstR[b]);
        if (slot < BCAP) bufR[(size_t)b * BCAP + slot] = sortedR[i];
        int b2 = bOfS[i];
        int slot2 = baseS[b2] + (i - lstS[b2]);
        if (slot2 < BCAP) bufS[(size_t)b2 * BCAP + slot2] = sortedS[i];
    }
}

// ---------------- pass 2: per-bucket CSR + degR/inv_r + inv_s + xs prep (256 nodes/bucket) ----------------
__global__ void k_pass2(const unsigned* __restrict__ bufR, const unsigned char* __restrict__ bufS,
                        const int* __restrict__ gCntR, const int* __restrict__ gCntS,
                        const float* __restrict__ x,
                        int* __restrict__ csr, int* __restrict__ cur, int* __restrict__ degR,
                        float* __restrict__ inv_r, float* __restrict__ inv_s,
                        bf16t* __restrict__ xs, int nN, int nB) {
    __shared__ int hist[256], incl[256], curs[256], histS[256];
    __shared__ int sm[256];
    __shared__ int gex[NBMAX];
    int t = threadIdx.x;
    int b = blockIdx.x;
    // inline exclusive scan of gCntR -> global edge base per bucket
    {
        int c0 = (2 * t < nB) ? gCntR[2 * t] : 0;
        int c1 = (2 * t + 1 < nB) ? gCntR[2 * t + 1] : 0;
        int ps = c0 + c1;
        sm[t] = ps;
        __syncthreads();
        for (int off = 1; off < 256; off <<= 1) {
            int y = (t >= off) ? sm[t - off] : 0;
            __syncthreads();
            sm[t] += y;
            __syncthreads();
        }
        int ex = sm[t] - ps;
        gex[2 * t] = ex;
        gex[2 * t + 1] = ex + c0;
    }
    hist[t] = 0; curs[t] = 0; histS[t] = 0;
    __syncthreads();
    int gb = gex[b];
    int cnt = gCntR[b];
    const unsigned* buf = bufR + (size_t)b * BCAP;
    for (int i = t; i < cnt; i += 256) atomicAdd(&hist[buf[i] >> 24], 1);
    __syncthreads();
    int v = hist[t];
    sm[t] = v;
    __syncthreads();
    for (int off = 1; off < 256; off <<= 1) {
        int y = (t >= off) ? sm[t - off] : 0;
        __syncthreads();
        sm[t] += y;
        __syncthreads();
    }
    incl[t] = sm[t];  // inclusive scan of bin counts
    __syncthreads();
    int n0 = b << 8;
    int n = n0 + t;
    if (n < nN) {
        degR[n] = v;
        cur[n] = gb + incl[t];  // end offset (consumers use cur-deg)
        inv_r[n] = rsqrtf(fmaxf((float)v, 1.f));
    }
    for (int i = t; i < cnt; i += 256) {
        unsigned p = buf[i];
        int rl = p >> 24;
        int s = p & 0xFFFFFF;
        int pos = gb + (incl[rl] - hist[rl]) + atomicAdd(&curs[rl], 1);
        csr[pos] = s;  // contiguous ~16KB window per block
    }
    // ---- sender part: out-degree -> inv_s + xs prep (bf16) ----
    int cntS = gCntS[b];
    const unsigned char* bufs = bufS + (size_t)b * BCAP;
    for (int i = t; i < cntS; i += 256) atomicAdd(&histS[bufs[i]], 1);
    __syncthreads();
    if (n < nN) {
        float is = rsqrtf(fmaxf((float)histS[t], 1.f));
        inv_s[n] = is;
        float w[9];
#pragma unroll
        for (int k = 0; k < 9; k++) w[k] = x[(size_t)n * 9 + k] * is;
        uint4 pa, pb;
        pa.x = pk2(w[0], w[1]); pa.y = pk2(w[2], w[3]);
        pa.z = pk2(w[4], w[5]); pa.w = pk2(w[6], w[7]);
        pb.x = pk2(w[8], is);   pb.y = 0; pb.z = 0; pb.w = 0;
        uint4* o = (uint4*)(xs + (size_t)n * 16);
        o[0] = pa;
        o[1] = pb;
    }
}

// ---------------- fused layer-1 agg + dense: quarter-wave per node, 16 edges in flight ----------------
__global__ void k_h1f(const unsigned* __restrict__ xs32, const float* __restrict__ W1,
                      const float* __restrict__ b1,
                      const int* __restrict__ csr, const int* __restrict__ cur,
                      const int* __restrict__ degR, const float* __restrict__ inv_r,
                      const float* __restrict__ inv_s,
                      bf16t* __restrict__ h1s, float* __restrict__ warr, int nN) {
    __shared__ float Wl[9 * 64];
    __shared__ float bl[64];
    for (int i = threadIdx.x; i < 9 * 64; i += blockDim.x) Wl[i] = W1[i];
    if (threadIdx.x < 64) bl[threadIdx.x] = b1[threadIdx.x];
    __syncthreads();
    int lane = threadIdx.x & 63;
    int wave = threadIdx.x >> 6;
    int n = blockIdx.x * 16 + wave * 4 + (lane >> 4);
    int ql = lane & 15;
    int g = ql >> 2;      // edge slot within quarter (4 edges in parallel)
    int f2 = ql & 3;      // uint2 index into the 32B xs row
    int nc = min(n, nN - 1);
    int deg = degR[nc];
    int st = cur[nc] - deg;
    float4 A0 = {0.f, 0.f, 0.f, 0.f}, A1 = A0, A2 = A0, A3 = A0;
    int i = 0;
    for (; i + 16 <= deg; i += 16) {
        int ea = csr[st + i + g];
        int eb = csr[st + i + 4 + g];
        int ec = csr[st + i + 8 + g];
        int ed = csr[st + i + 12 + g];
        uint2 u0 = *(const uint2*)(xs32 + (size_t)ea * 8 + f2 * 2);
        uint2 u1 = *(const uint2*)(xs32 + (size_t)eb * 8 + f2 * 2);
        uint2 u2 = *(const uint2*)(xs32 + (size_t)ec * 8 + f2 * 2);
        uint2 u3 = *(const uint2*)(xs32 + (size_t)ed * 8 + f2 * 2);
        float2 a = up2(u0.x), b = up2(u0.y);
        A0.x += a.x; A0.y += a.y; A0.z += b.x; A0.w += b.y;
        a = up2(u1.x); b = up2(u1.y);
        A1.x += a.x; A1.y += a.y; A1.z += b.x; A1.w += b.y;
        a = up2(u2.x); b = up2(u2.y);
        A2.x += a.x; A2.y += a.y; A2.z += b.x; A2.w += b.y;
        a = up2(u3.x); b = up2(u3.y);
        A3.x += a.x; A3.y += a.y; A3.z += b.x; A3.w += b.y;
    }
    for (; i + 4 <= deg; i += 4) {
        int ea = csr[st + i + g];
        uint2 u0 = *(const uint2*)(xs32 + (size_t)ea * 8 + f2 * 2);
        float2 a = up2(u0.x), b = up2(u0.y);
        A0.x += a.x; A0.y += a.y; A0.z += b.x; A0.w += b.y;
    }
    if (g < deg - i) {
        int ea = csr[st + i + g];
        uint2 u0 = *(const uint2*)(xs32 + (size_t)ea * 8 + f2 * 2);
        float2 a = up2(u0.x), b = up2(u0.y);
        A1.x += a.x; A1.y += a.y; A1.z += b.x; A1.w += b.y;
    }
    float4 vq = {(A0.x + A1.x) + (A2.x + A3.x), (A0.y + A1.y) + (A2.y + A3.y),
                 (A0.z + A1.z) + (A2.z + A3.z), (A0.w + A1.w) + (A2.w + A3.w)};
    vq.x += __shfl_xor(vq.x, 4); vq.y += __shfl_xor(vq.y, 4);
    vq.z += __shfl_xor(vq.z, 4); vq.w += __shfl_xor(vq.w, 4);
    vq.x += __shfl_xor(vq.x, 8); vq.y += __shfl_xor(vq.y, 8);
    vq.z += __shfl_xor(vq.z, 8); vq.w += __shfl_xor(vq.w, 8);
    int base = lane & 48;
    float xv[9];
    xv[0] = __shfl(vq.x, base + 0); xv[1] = __shfl(vq.y, base + 0);
    xv[2] = __shfl(vq.z, base + 0); xv[3] = __shfl(vq.w, base + 0);
    xv[4] = __shfl(vq.x, base + 1); xv[5] = __shfl(vq.y, base + 1);
    xv[6] = __shfl(vq.z, base + 1); xv[7] = __shfl(vq.w, base + 1);
    xv[8] = __shfl(vq.x, base + 2);
    float w = __shfl(vq.y, base + 2);
    float ir = inv_r[nc];
    float is = inv_s[nc];
    int c0 = ql * 4;
    float acc[4];
#pragma unroll
    for (int j = 0; j < 4; j++) acc[j] = w * bl[c0 + j];
#pragma unroll
    for (int k = 0; k < 9; k++) {
        float4 wv = *(const float4*)(Wl + k * 64 + c0);
        acc[0] += xv[k] * wv.x;
        acc[1] += xv[k] * wv.y;
        acc[2] += xv[k] * wv.z;
        acc[3] += xv[k] * wv.w;
    }
    if (n < nN) {
        float v0 = fmaxf(acc[0] * ir, 0.f) * is;
        float v1 = fmaxf(acc[1] * ir, 0.f) * is;
        float v2 = fmaxf(acc[2] * ir, 0.f) * is;
        float v3 = fmaxf(acc[3] * ir, 0.f) * is;
        uint2 pv;
        pv.x = pk2(v0, v1);
        pv.y = pk2(v2, v3);
        *(uint2*)(h1s + (size_t)n * 64 + c0) = pv;
        if (ql == 0) warr[n] = w;
    }
}

// ---------------- fused layer-2 gather + MFMA 64->128->2 ----------------
// block = 64 nodes (4 waves x 16). Phase 1: wave gathers its 16 nodes into LDS rows
// (stride 36 dwords -> balanced ds_read_b128; rows wave-private, no z barrier).
// Phase 2: MFMA 16x16x32 with A from LDS, epilogue bias/relu/scales, dot W3, write t.
__global__ void k_l2f(const unsigned* __restrict__ h32, const bf16t* __restrict__ W2f,
                      const float* __restrict__ b2, const float* __restrict__ W3,
                      const float* __restrict__ inv_r, const float* __restrict__ inv_s,
                      const float* __restrict__ warr,
                      const int* __restrict__ csr, const int* __restrict__ cur,
                      const int* __restrict__ degR,
                      float* __restrict__ t, float* __restrict__ dout, int outSize, int nN) {
    __shared__ float b2l[128];
    __shared__ float W3l[256];
    __shared__ unsigned zl[64 * 36];  // 64 rows x 144B
    for (int i = threadIdx.x; i < 128; i += blockDim.x) b2l[i] = b2[i];
    for (int i = threadIdx.x; i < 256; i += blockDim.x) W3l[i] = W3[i];
    if (blockIdx.x == 0 && threadIdx.x < outSize) dout[threadIdx.x] = 0.f;  // runs before k_poolg
    int lane = threadIdx.x & 63;
    int wave = threadIdx.x >> 6;
    int n0w = blockIdx.x * 64 + wave * 16;
    int q = lane >> 4;    // edge slot (4 edges in parallel)
    int ql = lane & 15;   // uint2 index into the 128B row
    for (int j = 0; j < 16; j++) {
        int nc = min(n0w + j, nN - 1);
        int deg = degR[nc];
        int st = cur[nc] - deg;
        float4 A0 = {0.f, 0.f, 0.f, 0.f}, A1 = A0, A2 = A0, A3 = A0;
        int i = 0;
        for (; i + 16 <= deg; i += 16) {
            int ea = csr[st + i + q];
            int eb = csr[st + i + 4 + q];
            int ec = csr[st + i + 8 + q];
            int ed = csr[st + i + 12 + q];
            uint2 u0 = *(const uint2*)(h32 + (size_t)ea * 32 + ql * 2);
            uint2 u1 = *(const uint2*)(h32 + (size_t)eb * 32 + ql * 2);
            uint2 u2 = *(const uint2*)(h32 + (size_t)ec * 32 + ql * 2);
            uint2 u3 = *(const uint2*)(h32 + (size_t)ed * 32 + ql * 2);
            float2 a = up2(u0.x), b = up2(u0.y);
            A0.x += a.x; A0.y += a.y; A0.z += b.x; A0.w += b.y;
            a = up2(u1.x); b = up2(u1.y);
            A1.x += a.x; A1.y += a.y; A1.z += b.x; A1.w += b.y;
            a = up2(u2.x); b = up2(u2.y);
            A2.x += a.x; A2.y += a.y; A2.z += b.x; A2.w += b.y;
            a = up2(u3.x); b = up2(u3.y);
            A3.x += a.x; A3.y += a.y; A3.z += b.x; A3.w += b.y;
        }
        for (; i + 4 <= deg; i += 4) {
            int ea = csr[st + i + q];
            uint2 u0 = *(const uint2*)(h32 + (size_t)ea * 32 + ql * 2);
            float2 a = up2(u0.x), b = up2(u0.y);
            A0.x += a.x; A0.y += a.y; A0.z += b.x; A0.w += b.y;
        }
        if (q < deg - i) {
            int ea = csr[st + i + q];
            uint2 u0 = *(const uint2*)(h32 + (size_t)ea * 32 + ql * 2);
            float2 a = up2(u0.x), b = up2(u0.y);
            A1.x += a.x; A1.y += a.y; A1.z += b.x; A1.w += b.y;
        }
        float4 v = {(A0.x + A1.x) + (A2.x + A3.x), (A0.y + A1.y) + (A2.y + A3.y),
                    (A0.z + A1.z) + (A2.z + A3.z), (A0.w + A1.w) + (A2.w + A3.w)};
        v.x += __shfl_xor(v.x, 16); v.y += __shfl_xor(v.y, 16);
        v.z += __shfl_xor(v.z, 16); v.w += __shfl_xor(v.w, 16);
        v.x += __shfl_xor(v.x, 32); v.y += __shfl_xor(v.y, 32);
        v.z += __shfl_xor(v.z, 32); v.w += __shfl_xor(v.w, 32);
        if (q == 0) {
            uint2 pv;
            pv.x = pk2(v.x, v.y);
            pv.y = pk2(v.z, v.w);
            *(uint2*)(zl + (wave * 16 + j) * 36 + ql * 2) = pv;
        }
    }
    __syncthreads();  // for b2l/W3l (z rows are wave-private)
    int m = ql;
    int row = wave * 16 + m;
    short8 afr0 = *(const short8*)(zl + row * 36 + q * 4);
    short8 afr1 = *(const short8*)(zl + row * 36 + 16 + q * 4);
    float w4[4], ir4[4], is4[4];
#pragma unroll
    for (int reg = 0; reg < 4; reg++) {
        int nr = min(n0w + q * 4 + reg, nN - 1);
        w4[reg] = warr[nr];
        ir4[reg] = inv_r[nr];
        is4[reg] = inv_s[nr];
    }
    float p0[4] = {0.f, 0.f, 0.f, 0.f}, p1[4] = {0.f, 0.f, 0.f, 0.f};
#pragma unroll
    for (int nt = 0; nt < 8; nt++) {
        short8 b0 = *(const short8*)(W2f + ((size_t)(nt * 2 + 0) * 64 + lane) * 8);
        short8 b1 = *(const short8*)(W2f + ((size_t)(nt * 2 + 1) * 64 + lane) * 8);
        f32x4 acc = {0.f, 0.f, 0.f, 0.f};
        acc = __builtin_amdgcn_mfma_f32_16x16x32_bf16(afr0, b0, acc, 0, 0, 0);
        acc = __builtin_amdgcn_mfma_f32_16x16x32_bf16(afr1, b1, acc, 0, 0, 0);
        int col = nt * 16 + m;
        float bc = b2l[col];
        float w30 = W3l[col * 2 + 0];
        float w31 = W3l[col * 2 + 1];
#pragma unroll
        for (int reg = 0; reg < 4; reg++) {
            float h = fmaxf((acc[reg] + w4[reg] * bc) * ir4[reg], 0.f) * is4[reg];
            p0[reg] += h * w30;
            p1[reg] += h * w31;
        }
    }
#pragma unroll
    for (int mask = 1; mask < 16; mask <<= 1) {
#pragma unroll
        for (int reg = 0; reg < 4; reg++) {
            p0[reg] += __shfl_xor(p0[reg], mask);
            p1[reg] += __shfl_xor(p1[reg], mask);
        }
    }
    if (m == 0) {
#pragma unroll
        for (int reg = 0; reg < 4; reg++) {
            int nr = n0w + q * 4 + reg;
            if (nr < nN) *(float2*)(t + (size_t)nr * 2) = make_float2(p0[reg], p1[reg]);
        }
    }
}

// ---------------- pooling (node-parallel over CSR), unroll x4 ----------------
__global__ void k_poolg(const float* __restrict__ t, const float* __restrict__ inv_r,
                        const float* __restrict__ warr, const float* __restrict__ b3,
                        const int* __restrict__ csr, const int* __restrict__ cur,
                        const int* __restrict__ degR, const int* __restrict__ batch,
                        float* out, int nN, int outSize) {
    __shared__ float sm[256];
    for (int i = threadIdx.x; i < 256; i += blockDim.x) sm[i] = 0.f;
    __syncthreads();
    float b30 = b3[0], b31 = b3[1];
    int n = blockIdx.x * blockDim.x + threadIdx.x;
    if (n < nN) {
        int deg = degR[n];
        int st = cur[n] - deg;
        float a0 = 0.f, a1 = 0.f, c0 = 0.f, c1 = 0.f;
        float d0 = 0.f, d1 = 0.f, e0 = 0.f, e1 = 0.f;
        int i = 0;
        for (; i + 4 <= deg; i += 4) {
            int sa = csr[st + i], sb = csr[st + i + 1];
            int sc = csr[st + i + 2], sd = csr[st + i + 3];
            float2 va = ((const float2*)t)[sa];
            float2 vb = ((const float2*)t)[sb];
            float2 vc = ((const float2*)t)[sc];
            float2 vd = ((const float2*)t)[sd];
            a0 += va.x; a1 += va.y;
            c0 += vb.x; c1 += vb.y;
            d0 += vc.x; d1 += vc.y;
            e0 += vd.x; e1 += vd.y;
        }
        for (; i < deg; i++) {
            float2 va = ((const float2*)t)[csr[st + i]];
            a0 += va.x; a1 += va.y;
        }
        float ir = inv_r[n];
        float wb = warr[n] * ir;
        int g = batch[n];
        atomicAdd(&sm[2 * g + 0], ((a0 + c0) + (d0 + e0)) * ir + wb * b30);
        atomicAdd(&sm[2 * g + 1], ((a1 + c1) + (d1 + e1)) * ir + wb * b31);
    }
    __syncthreads();
    for (int i = threadIdx.x; i < outSize; i += blockDim.x) atomicAdd(&out[i], sm[i]);
}

extern "C" void kernel_launch(void* const* d_in, const int* in_sizes, int n_in,
                              void* d_out, int out_size, void* d_ws, size_t ws_size,
                              hipStream_t stream) {
    const float* x     = (const float*)d_in[0];
    const int*   S     = (const int*)d_in[1];
    const int*   R     = (const int*)d_in[2];
    const int*   batch = (const int*)d_in[3];
    const float* W1 = (const float*)d_in[5];
    const float* b1 = (const float*)d_in[6];
    const float* W2 = (const float*)d_in[7];
    const float* b2 = (const float*)d_in[8];
    const float* W3 = (const float*)d_in[9];
    const float* b3 = (const float*)d_in[10];

    int nN = in_sizes[0] / 9;
    int nE = in_sizes[1];
    int nB = (nN + 255) / 256;  // 256-node buckets; requires nB <= NBMAX

    char* ws = (char*)d_ws;
    int*   cur   = (int*)ws;                          // nN
    int*   degR  = cur + nN;                          // nN
    float* inv_s = (float*)(degR + nN);               // nN
    float* inv_r = inv_s + nN;                        // nN
    float* warr  = inv_r + nN;                        // nN
    int*   gCntR = (int*)(warr + nN);                 // NBMAX
    int*   gCntS = gCntR + NBMAX;                     // NBMAX
    int*   csr   = gCntS + NBMAX;                     // nE
    bf16t* xs    = (bf16t*)(csr + nE);                // nN*16 bf16 (3.2 MB)
    bf16t* W2f   = xs + (size_t)nN * 16;              // 8192 bf16 (16 KB)
    char*  regA  = (char*)(W2f + 8192);
    // aliasing (bufR/bufS dead after k_pass2; h1s written by k_h1f afterwards)
    unsigned*      bufR = (unsigned*)regA;                                // NBMAX*BCAP*4 = 10.5 MB
    unsigned char* bufS = (unsigned char*)(bufR + (size_t)NBMAX * BCAP);  // NBMAX*BCAP   = 2.6 MB
    bf16t* h1s = (bf16t*)regA;                        // nN*64 bf16 (12.8 MB)
    float* t   = (float*)(regA + (size_t)NBMAX * BCAP * 5);  // nN*2 fp32 (past both regions)

    const int B = 256;

    // ---- build: bucket sort (+W2 frag prep in extra blocks), then per-bucket CSR etc. ----
    hipMemsetAsync(gCntR, 0, 2 * NBMAX * 4, stream);
    k_bucket<<<516, B, 0, stream>>>(S, R, bufR, bufS, gCntR, gCntS, W2, W2f, nE, nB);
    k_pass2<<<nB, B, 0, stream>>>(bufR, bufS, gCntR, gCntS, x, csr, cur, degR,
                                  inv_r, inv_s, xs, nN, nB);

    // ---- layer 1: fused gather + 9->64 dense ----
    k_h1f<<<(nN + 15) / 16, B, 0, stream>>>((const unsigned*)xs, W1, b1, csr, cur, degR,
                                            inv_r, inv_s, h1s, warr, nN);

    // ---- layers 2+3: fused gather + MFMA 64->128->2 (also zeroes d_out) ----
    k_l2f<<<(nN + 63) / 64, B, 0, stream>>>((const unsigned*)h1s, W2f, b2, W3,
                                            inv_r, inv_s, warr, csr, cur, degR,
                                            t, (float*)d_out, out_size, nN);

    // ---- fused layer-3 aggregation + bias + pooling ----
    k_poolg<<<(nN + B - 1) / B, B, 0, stream>>>(t, inv_r, warr, b3, csr, cur, degR, batch,
                                                (float*)d_out, nN, out_size);
}